// Round 1
// baseline (2538.698 us; speedup 1.0000x reference)
//
#include <hip/hip_runtime.h>
#include <hip/hip_bf16.h>
#include <math.h>

namespace {
constexpr int Bn  = 2;
constexpr int Ln  = 2048;
constexpr int Dn  = 1024;
constexpr int Hn  = 16;
constexpr int DHn = 64;
constexpr int Mn  = Bn * Ln; // 4096
}

// ---------------------------------------------------------------------------
// GEMM: C[M][N] = X[M][K] @ W[N][K]^T + bias[N]
// 128x128 tile, BK=8, 256 threads, 8x8 micro-tile per thread, f32.
// ---------------------------------------------------------------------------
__global__ __launch_bounds__(256)
void gemm_xwt_bias(const float* __restrict__ X, const float* __restrict__ W,
                   const float* __restrict__ bias, float* __restrict__ C,
                   int Md, int Nd, int Kd)
{
    constexpr int BK = 8;
    __shared__ float Xs[BK][128];
    __shared__ float Ws[BK][128];
    const int t  = threadIdx.x;
    const int bm = blockIdx.y * 128;
    const int bn = blockIdx.x * 128;
    const int ty = t >> 4, tx = t & 15;
    const int lrow = t >> 1;
    const int lk4  = (t & 1) * 4;

    float acc[8][8];
#pragma unroll
    for (int i = 0; i < 8; ++i)
#pragma unroll
        for (int j = 0; j < 8; ++j) acc[i][j] = 0.f;

    const float* Xp = X + (size_t)(bm + lrow) * Kd + lk4;
    const float* Wp = W + (size_t)(bn + lrow) * Kd + lk4;

    for (int k0 = 0; k0 < Kd; k0 += BK) {
        float4 xv = *(const float4*)(Xp + k0);
        float4 wv = *(const float4*)(Wp + k0);
        __syncthreads();   // previous iteration's LDS reads complete
        Xs[lk4 + 0][lrow] = xv.x; Xs[lk4 + 1][lrow] = xv.y;
        Xs[lk4 + 2][lrow] = xv.z; Xs[lk4 + 3][lrow] = xv.w;
        Ws[lk4 + 0][lrow] = wv.x; Ws[lk4 + 1][lrow] = wv.y;
        Ws[lk4 + 2][lrow] = wv.z; Ws[lk4 + 3][lrow] = wv.w;
        __syncthreads();
#pragma unroll
        for (int kk = 0; kk < BK; ++kk) {
            float a[8], b[8];
            *(float4*)&a[0] = *(const float4*)&Xs[kk][ty * 8];
            *(float4*)&a[4] = *(const float4*)&Xs[kk][ty * 8 + 4];
            *(float4*)&b[0] = *(const float4*)&Ws[kk][tx * 8];
            *(float4*)&b[4] = *(const float4*)&Ws[kk][tx * 8 + 4];
#pragma unroll
            for (int i = 0; i < 8; ++i)
#pragma unroll
                for (int j = 0; j < 8; ++j)
                    acc[i][j] = fmaf(a[i], b[j], acc[i][j]);
        }
    }

#pragma unroll
    for (int i = 0; i < 8; ++i) {
        const int row = bm + ty * 8 + i;
#pragma unroll
        for (int j = 0; j < 8; j += 4) {
            const int col = bn + tx * 8 + j;
            float4 o;
            o.x = acc[i][j + 0] + bias[col + 0];
            o.y = acc[i][j + 1] + bias[col + 1];
            o.z = acc[i][j + 2] + bias[col + 2];
            o.w = acc[i][j + 3] + bias[col + 3];
            *(float4*)&C[(size_t)row * Nd + col] = o;
        }
    }
}

// ---------------------------------------------------------------------------
// Per-head Lorentz projection on rows of 64: elem0 := tsign*sqrt(1+sum(space^2)),
// whole row scaled by `scale`. One wave per head-row. For q: scale=0.25,
// tsign=-1 (folds score scale + Lorentz metric into stored q).
// ---------------------------------------------------------------------------
__global__ __launch_bounds__(256)
void lorentz_rows64(float* __restrict__ z, float scale, float tsign)
{
    const int lane = threadIdx.x & 63;
    const int w    = threadIdx.x >> 6;
    const size_t base = ((size_t)blockIdx.x * 4 + w) * 64;
    float v = z[base + lane];
    float c = (lane == 0) ? 0.f : v * v;
#pragma unroll
    for (int off = 32; off; off >>= 1) c += __shfl_xor(c, off);
    float tval = sqrtf(1.0f + c);
    float o = (lane == 0) ? tsign * tval : v;
    z[base + lane] = o * scale;
}

// ---------------------------------------------------------------------------
// Flash attention per (b,h). Block = 512 thr (8 waves), 64 q-rows/block
// (8 per wave), K/V chunks of 64 staged in LDS (pitch 65 -> conflict-free
// scalar reads). scores = dot(q_stored, k). Epilogue fuses mu = acc/l and
// Lorentz normalization, writes cat.
// ---------------------------------------------------------------------------
__global__ __launch_bounds__(512)
void attn_kernel(const float* __restrict__ qs, const float* __restrict__ ks,
                 const float* __restrict__ vs, float* __restrict__ cat)
{
    constexpr int KC = 64, QR = 8, QB = 64, PITCH = 65;
    __shared__ float k_s[KC * PITCH];
    __shared__ float v_s[KC * PITCH];
    __shared__ float q_s[QB * 64];

    const int t    = threadIdx.x;
    const int lane = t & 63;
    const int w    = t >> 6;
    const int b    = blockIdx.x >> 4;
    const int h    = blockIdx.x & 15;
    const int q0   = blockIdx.y * QB;

    const float* qbase = qs + ((size_t)b * Ln) * Dn + h * DHn;
    const float* kbase = ks + ((size_t)b * Ln) * Dn + h * DHn;
    const float* vbase = vs + ((size_t)b * Ln) * Dn + h * DHn;

    // stage the 64 q rows once
#pragma unroll
    for (int i = 0; i < 2; ++i) {
        int idx = i * 512 + t;
        int r   = idx >> 4;
        int c4  = (idx & 15) * 4;
        float4 qv = *(const float4*)&qbase[(size_t)(q0 + r) * Dn + c4];
        q_s[r * 64 + c4 + 0] = qv.x; q_s[r * 64 + c4 + 1] = qv.y;
        q_s[r * 64 + c4 + 2] = qv.z; q_s[r * 64 + c4 + 3] = qv.w;
    }

    float mrun[QR], lrun[QR], acc[QR];
#pragma unroll
    for (int r = 0; r < QR; ++r) { mrun[r] = -1e30f; lrun[r] = 0.f; acc[r] = 0.f; }

    for (int ch = 0; ch < Ln / KC; ++ch) {
        __syncthreads();   // prior chunk's k_s/v_s reads complete (also orders q_s staging)
#pragma unroll
        for (int i = 0; i < 2; ++i) {
            int idx = i * 512 + t;
            int r   = idx >> 4;
            int c4  = (idx & 15) * 4;
            const size_t g = (size_t)(ch * KC + r) * Dn + c4;
            float4 kv = *(const float4*)&kbase[g];
            float4 vv = *(const float4*)&vbase[g];
            k_s[r * PITCH + c4 + 0] = kv.x; k_s[r * PITCH + c4 + 1] = kv.y;
            k_s[r * PITCH + c4 + 2] = kv.z; k_s[r * PITCH + c4 + 3] = kv.w;
            v_s[r * PITCH + c4 + 0] = vv.x; v_s[r * PITCH + c4 + 1] = vv.y;
            v_s[r * PITCH + c4 + 2] = vv.z; v_s[r * PITCH + c4 + 3] = vv.w;
        }
        __syncthreads();

        // QK^T: lane = k-row within chunk
        float s[QR];
#pragma unroll
        for (int r = 0; r < QR; ++r) s[r] = 0.f;
#pragma unroll 4
        for (int d = 0; d < DHn; ++d) {
            float kd = k_s[lane * PITCH + d];       // bank (lane+d)%32: conflict-free
#pragma unroll
            for (int r = 0; r < QR; ++r)
                s[r] = fmaf(q_s[(w * QR + r) * 64 + d], kd, s[r]);  // broadcast
        }

        // online softmax (per q-row, across the 64 lanes = 64 k's)
        float p[QR], scl[QR];
#pragma unroll
        for (int r = 0; r < QR; ++r) {
            float cm = s[r];
#pragma unroll
            for (int off = 32; off; off >>= 1) cm = fmaxf(cm, __shfl_xor(cm, off));
            float mnew = fmaxf(mrun[r], cm);
            scl[r] = __expf(mrun[r] - mnew);
            p[r]   = __expf(s[r] - mnew);
            float ps = p[r];
#pragma unroll
            for (int off = 32; off; off >>= 1) ps += __shfl_xor(ps, off);
            lrun[r] = lrun[r] * scl[r] + ps;
            mrun[r] = mnew;
            acc[r] *= scl[r];
        }

        // PV: lane owns output dim = lane
#pragma unroll 4
        for (int j = 0; j < KC; ++j) {
            float vv = v_s[j * PITCH + lane];       // bank (j+lane)%32: conflict-free
#pragma unroll
            for (int r = 0; r < QR; ++r)
                acc[r] = fmaf(__shfl(p[r], j), vv, acc[r]);
        }
    }

    // epilogue: mu = acc/l, Lorentz-normalize, write cat
#pragma unroll
    for (int r = 0; r < QR; ++r) {
        float mu = acc[r] / lrun[r];
        float c  = mu * mu;
        if (lane == 0) c = -c;                      // sum - 2*mu0^2
#pragma unroll
        for (int off = 32; off; off >>= 1) c += __shfl_xor(c, off);
        float nrm = sqrtf(fmaxf(fabsf(c), 1e-6f));
        size_t row = (size_t)q0 + w * QR + r;
        cat[((size_t)b * Ln + row) * Dn + h * DHn + lane] = mu / nrm;
    }
}

// ---------------------------------------------------------------------------
// Full-row (D=1024) Lorentz projection on the final output: elem0 :=
// sqrt(1 + sum_{i>=1} z_i^2). One 256-thread block per row.
// ---------------------------------------------------------------------------
__global__ __launch_bounds__(256)
void lorentz_row_full(float* __restrict__ z)
{
    __shared__ float red[4];
    const int t = threadIdx.x;
    const size_t base = (size_t)blockIdx.x * Dn;
    float4 v = *(const float4*)&z[base + t * 4];
    if (t == 0) v.x = 0.f;
    float ssq = v.x * v.x + v.y * v.y + v.z * v.z + v.w * v.w;
#pragma unroll
    for (int off = 32; off; off >>= 1) ssq += __shfl_xor(ssq, off);
    if ((t & 63) == 0) red[t >> 6] = ssq;
    __syncthreads();
    if (t == 0) z[base] = sqrtf(1.0f + red[0] + red[1] + red[2] + red[3]);
}

// ---------------------------------------------------------------------------
extern "C" void kernel_launch(void* const* d_in, const int* in_sizes, int n_in,
                              void* d_out, int out_size, void* d_ws, size_t ws_size,
                              hipStream_t stream)
{
    const float* query = (const float*)d_in[0];
    const float* key_  = (const float*)d_in[1];
    const float* value = (const float*)d_in[2];
    const float* W_Q   = (const float*)d_in[3];
    const float* b_Q   = (const float*)d_in[4];
    const float* W_K   = (const float*)d_in[5];
    const float* b_K   = (const float*)d_in[6];
    const float* W_V   = (const float*)d_in[7];
    const float* b_V   = (const float*)d_in[8];
    const float* W_O   = (const float*)d_in[9];
    const float* b_O   = (const float*)d_in[10];
    float* out = (float*)d_out;

    float* q   = (float*)d_ws;               // [M][D] each, f32
    float* k   = q + (size_t)Mn * Dn;
    float* v   = k + (size_t)Mn * Dn;
    float* cat = v + (size_t)Mn * Dn;        // total 64 MB of d_ws

    dim3 ggrid(Dn / 128, Mn / 128);          // (8, 32)
    gemm_xwt_bias<<<ggrid, 256, 0, stream>>>(query, W_Q, b_Q, q, Mn, Dn, Dn);
    gemm_xwt_bias<<<ggrid, 256, 0, stream>>>(key_,  W_K, b_K, k, Mn, Dn, Dn);
    gemm_xwt_bias<<<ggrid, 256, 0, stream>>>(value, W_V, b_V, v, Mn, Dn, Dn);

    // q: fold time-negation (Lorentz metric) and 0.25 score scale into storage
    lorentz_rows64<<<Mn * Hn / 4, 256, 0, stream>>>(q, 0.25f, -1.f);
    lorentz_rows64<<<Mn * Hn / 4, 256, 0, stream>>>(k, 1.f, 1.f);
    lorentz_rows64<<<Mn * Hn / 4, 256, 0, stream>>>(v, 1.f, 1.f);

    dim3 agrid(Bn * Hn, Ln / 64);            // (32, 32)
    attn_kernel<<<agrid, 512, 0, stream>>>(q, k, v, cat);

    gemm_xwt_bias<<<ggrid, 256, 0, stream>>>(cat, W_O, b_O, out, Mn, Dn, Dn);
    lorentz_row_full<<<Mn, 256, 0, stream>>>(out);
}

// Round 2
// 255.868 us; speedup vs baseline: 9.9219x; 9.9219x over previous
//
#include <hip/hip_runtime.h>
#include <math.h>

namespace {
constexpr int Ln = 2048;
constexpr int Dn = 1024;
constexpr int Mn = 4096;   // B*L
}

typedef unsigned short u16;
typedef __attribute__((ext_vector_type(4))) float f32x4;
typedef __attribute__((ext_vector_type(8))) __bf16 bf16x8;
typedef __attribute__((ext_vector_type(4))) unsigned short u16x4;
typedef __attribute__((ext_vector_type(4))) unsigned int u32x4;

__device__ __forceinline__ u16 f2bf(float f) {
    union { float f; unsigned u; } cv; cv.f = f;
    unsigned u = cv.u + 0x7fffu + ((cv.u >> 16) & 1u);
    return (u16)(u >> 16);
}

__device__ __forceinline__ void gload16(const void* g, void* l) {
    __builtin_amdgcn_global_load_lds(
        (const __attribute__((address_space(1))) unsigned int*)g,
        (__attribute__((address_space(3))) unsigned int*)l, 16, 0, 0);
}

// ---------------------------------------------------------------------------
// f32 -> bf16 convert (vectorized: 4 floats / thread)
// ---------------------------------------------------------------------------
__global__ __launch_bounds__(256)
void cvt_bf16(const float* __restrict__ in, u16* __restrict__ out, int n4)
{
    int i = blockIdx.x * 256 + threadIdx.x;
    if (i >= n4) return;
    f32x4 v = ((const f32x4*)in)[i];
    u16x4 o;
#pragma unroll
    for (int j = 0; j < 4; ++j) o[j] = f2bf(v[j]);
    ((u16x4*)out)[i] = o;
}

// ---------------------------------------------------------------------------
// bf16 MFMA GEMM (m97 structure): C[M][1024] = A[M][1024] @ B[1024][1024]^T + bias
// 128x128 tile, BK=32, 256 thr (4 waves, 2x2), wave tile 64x64 = 4x4 frags.
// mode 0: write f32 C.
// mode 1: fused per-head (64-col) Lorentz projection; write bf16 to
//         transposed layout [b][h][l][64]; time := tsign*sqrt(1+ssq); *scale.
// ---------------------------------------------------------------------------
__global__ __launch_bounds__(256)
void gemm_bf16(const u16* __restrict__ A, const u16* __restrict__ B,
               const float* __restrict__ bias, void* __restrict__ Cout,
               int mode, float scale, float tsign)
{
    __shared__ u16 As[128 * 32];
    __shared__ u16 Bs[128 * 32];
    const int t = threadIdx.x;
    const int lane = t & 63, w = t >> 6;
    const int g = lane >> 4, c = lane & 15;
    const int wr = w >> 1, wc = w & 1;
    const int bm = blockIdx.y * 128, bn = blockIdx.x * 128;

    f32x4 acc[4][4];
    const f32x4 z4 = {0.f, 0.f, 0.f, 0.f};
#pragma unroll
    for (int i = 0; i < 4; ++i)
#pragma unroll
        for (int j = 0; j < 4; ++j) acc[i][j] = z4;

    for (int k0 = 0; k0 < Dn; k0 += 32) {
        __syncthreads();                       // prior iter's LDS reads done
#pragma unroll
        for (int s = 0; s < 2; ++s) {
            int ci = s * 256 + t;              // 0..511 chunk of 16B
            int r = ci >> 2, ks = (ci & 3) * 8;
            gload16(A + (size_t)(bm + r) * Dn + k0 + ks, &As[ci * 8]);
            gload16(B + (size_t)(bn + r) * Dn + k0 + ks, &Bs[ci * 8]);
        }
        __syncthreads();                       // staged data visible
        bf16x8 a[4], b[4];
#pragma unroll
        for (int mi = 0; mi < 4; ++mi)
            a[mi] = *(const bf16x8*)&As[(wr * 64 + mi * 16 + c) * 32 + g * 8];
#pragma unroll
        for (int ni = 0; ni < 4; ++ni)
            b[ni] = *(const bf16x8*)&Bs[(wc * 64 + ni * 16 + c) * 32 + g * 8];
#pragma unroll
        for (int mi = 0; mi < 4; ++mi)
#pragma unroll
            for (int ni = 0; ni < 4; ++ni)
                acc[mi][ni] = __builtin_amdgcn_mfma_f32_16x16x32_bf16(
                    a[mi], b[ni], acc[mi][ni], 0, 0, 0);
    }

    if (mode == 0) {
        float* Cf = (float*)Cout;
#pragma unroll
        for (int mi = 0; mi < 4; ++mi)
#pragma unroll
            for (int j = 0; j < 4; ++j) {
                size_t row = bm + wr * 64 + mi * 16 + g * 4 + j;
#pragma unroll
                for (int ni = 0; ni < 4; ++ni) {
                    int col = bn + wc * 64 + ni * 16 + c;
                    Cf[row * Dn + col] = acc[mi][ni][j] + bias[col];
                }
            }
    } else {
        u16* Ct = (u16*)Cout;
        const int hcb = bn + wc * 64;          // 64-aligned head col base
        const int h = hcb >> 6;
#pragma unroll
        for (int mi = 0; mi < 4; ++mi)
#pragma unroll
            for (int j = 0; j < 4; ++j) {
                int row = bm + wr * 64 + mi * 16 + g * 4 + j;
                float zv[4];
#pragma unroll
                for (int ni = 0; ni < 4; ++ni)
                    zv[ni] = acc[mi][ni][j] + bias[hcb + ni * 16 + c];
                float loc = zv[0]*zv[0] + zv[1]*zv[1] + zv[2]*zv[2] + zv[3]*zv[3];
                if (c == 0) loc -= 2.f * zv[0] * zv[0];   // drop time slot
#pragma unroll
                for (int off = 8; off; off >>= 1) loc += __shfl_xor(loc, off);
                float tval = sqrtf(1.f + loc);
                int bb = row >> 11, ll = row & 2047;
                u16* dst = Ct + (((size_t)bb * 16 + h) * Ln + ll) * 64;
#pragma unroll
                for (int ni = 0; ni < 4; ++ni) {
                    float val = (ni == 0 && c == 0) ? tsign * tval : zv[ni];
                    dst[ni * 16 + c] = f2bf(val * scale);
                }
            }
    }
}

// ---------------------------------------------------------------------------
// MFMA flash attention per (b,h). 256 thr (4 waves), 128 q-rows/block
// (32/wave), KV chunk 64. K/Vt/P in XOR-swizzled LDS (conflict-free b128).
// Epilogue fuses mu normalization, writes bf16 cat [b][l][h*64+d].
// ---------------------------------------------------------------------------
__global__ __launch_bounds__(256)
void attn_mfma(const u16* __restrict__ qt, const u16* __restrict__ kt,
               const u16* __restrict__ vt, u16* __restrict__ cat)
{
    __shared__ u16 k_s[64 * 64];        // [n][k], swizzled
    __shared__ u16 v_s[64 * 64];        // transposed [d][kchunk], swizzled
    __shared__ u16 p_s[4 * 32 * 64];    // per-wave [q][k], swizzled

    const int t = threadIdx.x;
    const int lane = t & 63, w = t >> 6;
    const int g = lane >> 4, c = lane & 15;
    const int bh = blockIdx.x;
    const int q0 = blockIdx.y * 128;
    const size_t base = (size_t)bh * Ln * 64;
    const u16* Q = qt + base;
    const u16* K = kt + base;
    const u16* V = vt + base;

    // Q fragments live in registers across the whole KV sweep
    bf16x8 qa[2][2];
#pragma unroll
    for (int mi = 0; mi < 2; ++mi)
#pragma unroll
        for (int kk = 0; kk < 2; ++kk)
            qa[mi][kk] = *(const bf16x8*)(Q + (size_t)(q0 + w * 32 + mi * 16 + c) * 64
                                            + kk * 32 + g * 8);

    f32x4 o[2][4];
    float mrow[2][4], lrow[2][4];
    const f32x4 z4 = {0.f, 0.f, 0.f, 0.f};
#pragma unroll
    for (int mi = 0; mi < 2; ++mi) {
#pragma unroll
        for (int j = 0; j < 4; ++j) { mrow[mi][j] = -1e30f; lrow[mi][j] = 0.f; }
#pragma unroll
        for (int di = 0; di < 4; ++di) o[mi][di] = z4;
    }

    const int vr0 = (t >> 4) * 4, vd0 = (t & 15) * 4;

    for (int ch = 0; ch < Ln / 64; ++ch) {
        // ---- issue global loads early (regs), then stage after barrier ----
        u32x4 kreg[2];
#pragma unroll
        for (int s = 0; s < 2; ++s) {
            int seg = s * 256 + t;
            int r = seg >> 3, sl = seg & 7;
            kreg[s] = *(const u32x4*)(K + (size_t)(ch * 64 + r) * 64 + sl * 8);
        }
        u16x4 vreg[4];
#pragma unroll
        for (int i = 0; i < 4; ++i)
            vreg[i] = *(const u16x4*)(V + (size_t)(ch * 64 + vr0 + i) * 64 + vd0);

        __syncthreads();                       // prior chunk's LDS reads done
#pragma unroll
        for (int s = 0; s < 2; ++s) {
            int seg = s * 256 + t;
            int r = seg >> 3, sl = seg & 7;
            *(u32x4*)&k_s[r * 64 + 8 * (sl ^ (r & 7))] = kreg[s];
        }
#pragma unroll
        for (int j = 0; j < 4; ++j) {          // 4x4 micro-transpose of V
            int d = vd0 + j;
            u16x4 tv = { vreg[0][j], vreg[1][j], vreg[2][j], vreg[3][j] };
            *(u16x4*)&v_s[d * 64 + (((vr0 * 2) ^ ((d & 7) << 4)) >> 1)] = tv;
        }
        __syncthreads();                       // K/Vt ready

        // ---- QK^T ----
        f32x4 sf[2][4];
#pragma unroll
        for (int mi = 0; mi < 2; ++mi)
#pragma unroll
            for (int ni = 0; ni < 4; ++ni) sf[mi][ni] = z4;
#pragma unroll
        for (int kk = 0; kk < 2; ++kk) {
            bf16x8 kb[4];
#pragma unroll
            for (int ni = 0; ni < 4; ++ni) {
                int n = ni * 16 + c;
                kb[ni] = *(const bf16x8*)&k_s[n * 64 + (((kk * 64 + g * 16) ^ ((n & 7) << 4)) >> 1)];
            }
#pragma unroll
            for (int mi = 0; mi < 2; ++mi)
#pragma unroll
                for (int ni = 0; ni < 4; ++ni)
                    sf[mi][ni] = __builtin_amdgcn_mfma_f32_16x16x32_bf16(
                        qa[mi][kk], kb[ni], sf[mi][ni], 0, 0, 0);
        }

        // ---- online softmax + P (bf16, swizzled per-wave LDS) ----
#pragma unroll
        for (int mi = 0; mi < 2; ++mi)
#pragma unroll
            for (int j = 0; j < 4; ++j) {
                float mx = fmaxf(fmaxf(sf[mi][0][j], sf[mi][1][j]),
                                 fmaxf(sf[mi][2][j], sf[mi][3][j]));
#pragma unroll
                for (int off = 8; off; off >>= 1) mx = fmaxf(mx, __shfl_xor(mx, off));
                float mnew = fmaxf(mrow[mi][j], mx);
                float scl = __expf(mrow[mi][j] - mnew);
                mrow[mi][j] = mnew;
                int ql = mi * 16 + g * 4 + j;
                int swz = (ql & 7) << 4;
                float ps = 0.f;
#pragma unroll
                for (int ni = 0; ni < 4; ++ni) {
                    float p = __expf(sf[mi][ni][j] - mnew);
                    ps += p;
                    p_s[w * 2048 + ql * 64 + ((((ni * 16 + c) * 2) ^ swz) >> 1)] = f2bf(p);
                }
#pragma unroll
                for (int off = 8; off; off >>= 1) ps += __shfl_xor(ps, off);
                lrow[mi][j] = lrow[mi][j] * scl + ps;
#pragma unroll
                for (int di = 0; di < 4; ++di) o[mi][di][j] *= scl;
            }

        // ---- PV ----
#pragma unroll
        for (int kk = 0; kk < 2; ++kk) {
            bf16x8 pa[2];
#pragma unroll
            for (int mi = 0; mi < 2; ++mi) {
                int ql = mi * 16 + c;
                pa[mi] = *(const bf16x8*)&p_s[w * 2048 + ql * 64
                            + (((kk * 64 + g * 16) ^ ((ql & 7) << 4)) >> 1)];
            }
#pragma unroll
            for (int di = 0; di < 4; ++di) {
                int d = di * 16 + c;
                bf16x8 vb = *(const bf16x8*)&v_s[d * 64
                            + (((kk * 64 + g * 16) ^ ((d & 7) << 4)) >> 1)];
#pragma unroll
                for (int mi = 0; mi < 2; ++mi)
                    o[mi][di] = __builtin_amdgcn_mfma_f32_16x16x32_bf16(
                        pa[mi], vb, o[mi][di], 0, 0, 0);
            }
        }
    }

    // ---- epilogue: mu = o/l, Lorentz normalize, write bf16 cat ----
    const int b = bh >> 4, h = bh & 15;
#pragma unroll
    for (int mi = 0; mi < 2; ++mi)
#pragma unroll
        for (int j = 0; j < 4; ++j) {
            float linv = 1.f / lrow[mi][j];
            float mu[4];
#pragma unroll
            for (int di = 0; di < 4; ++di) mu[di] = o[mi][di][j] * linv;
            float loc = mu[0]*mu[0] + mu[1]*mu[1] + mu[2]*mu[2] + mu[3]*mu[3];
            if (c == 0) loc -= 2.f * mu[0] * mu[0];
#pragma unroll
            for (int off = 8; off; off >>= 1) loc += __shfl_xor(loc, off);
            float rn = 1.f / sqrtf(fmaxf(fabsf(loc), 1e-6f));
            int row = q0 + w * 32 + mi * 16 + g * 4 + j;
            u16* dst = cat + ((size_t)b * Ln + row) * Dn + h * 64;
#pragma unroll
            for (int di = 0; di < 4; ++di)
                dst[di * 16 + c] = f2bf(mu[di] * rn);
        }
}

// ---------------------------------------------------------------------------
// Full-row (D=1024) Lorentz projection on f32 output rows.
// ---------------------------------------------------------------------------
__global__ __launch_bounds__(256)
void lorentz_row_full(float* __restrict__ z)
{
    __shared__ float red[4];
    const int t = threadIdx.x;
    const size_t base = (size_t)blockIdx.x * Dn;
    float4 v = *(const float4*)&z[base + t * 4];
    if (t == 0) v.x = 0.f;
    float ssq = v.x * v.x + v.y * v.y + v.z * v.z + v.w * v.w;
#pragma unroll
    for (int off = 32; off; off >>= 1) ssq += __shfl_xor(ssq, off);
    if ((t & 63) == 0) red[t >> 6] = ssq;
    __syncthreads();
    if (t == 0) z[base] = sqrtf(1.0f + red[0] + red[1] + red[2] + red[3]);
}

// ---------------------------------------------------------------------------
extern "C" void kernel_launch(void* const* d_in, const int* in_sizes, int n_in,
                              void* d_out, int out_size, void* d_ws, size_t ws_size,
                              hipStream_t stream)
{
    const float* query = (const float*)d_in[0];
    const float* key_  = (const float*)d_in[1];
    const float* value = (const float*)d_in[2];
    const float* W_Q   = (const float*)d_in[3];
    const float* b_Q   = (const float*)d_in[4];
    const float* W_K   = (const float*)d_in[5];
    const float* b_K   = (const float*)d_in[6];
    const float* W_V   = (const float*)d_in[7];
    const float* b_V   = (const float*)d_in[8];
    const float* W_O   = (const float*)d_in[9];
    const float* b_O   = (const float*)d_in[10];

    u16* xq = (u16*)d_ws;                      // bf16 inputs  [4096][1024]
    u16* xk = xq + (size_t)Mn * Dn;
    u16* xv = xk + (size_t)Mn * Dn;
    u16* wq = xv + (size_t)Mn * Dn;            // bf16 weights [1024][1024]
    u16* wk = wq + (size_t)Dn * Dn;
    u16* wv = wk + (size_t)Dn * Dn;
    u16* wo = wv + (size_t)Dn * Dn;
    u16* q_t = wo + (size_t)Dn * Dn;           // bf16 [b][h][l][64]
    u16* k_t = q_t + (size_t)Mn * Dn;
    u16* v_t = k_t + (size_t)Mn * Dn;
    u16* cat = v_t + (size_t)Mn * Dn;          // bf16 [b][l][1024]   (total 64 MB)

    const int n4x = Mn * Dn / 4, n4w = Dn * Dn / 4;
    cvt_bf16<<<n4x / 256, 256, 0, stream>>>(query, xq, n4x);
    cvt_bf16<<<n4x / 256, 256, 0, stream>>>(key_,  xk, n4x);
    cvt_bf16<<<n4x / 256, 256, 0, stream>>>(value, xv, n4x);
    cvt_bf16<<<n4w / 256, 256, 0, stream>>>(W_Q, wq, n4w);
    cvt_bf16<<<n4w / 256, 256, 0, stream>>>(W_K, wk, n4w);
    cvt_bf16<<<n4w / 256, 256, 0, stream>>>(W_V, wv, n4w);
    cvt_bf16<<<n4w / 256, 256, 0, stream>>>(W_O, wo, n4w);

    dim3 gg(Dn / 128, Mn / 128);               // (8, 32)
    // q: fold Lorentz metric (negate time) + 0.25 score scale into storage
    gemm_bf16<<<gg, 256, 0, stream>>>(xq, wq, b_Q, q_t, 1, 0.25f, -1.f);
    gemm_bf16<<<gg, 256, 0, stream>>>(xk, wk, b_K, k_t, 1, 1.f, 1.f);
    gemm_bf16<<<gg, 256, 0, stream>>>(xv, wv, b_V, v_t, 1, 1.f, 1.f);

    dim3 ag(32, Ln / 128);                     // (32, 16)
    attn_mfma<<<ag, 256, 0, stream>>>(q_t, k_t, v_t, cat);

    gemm_bf16<<<gg, 256, 0, stream>>>(cat, wo, b_O, d_out, 0, 1.f, 1.f);
    lorentz_row_full<<<Mn, 256, 0, stream>>>((float*)d_out);
}

// Round 3
// 230.221 us; speedup vs baseline: 11.0272x; 1.1114x over previous
//
#include <hip/hip_runtime.h>
#include <math.h>

namespace {
constexpr int Ln = 2048;
constexpr int Dn = 1024;
constexpr int Mn = 4096;   // B*L
constexpr float QSCALE = 0.25f * 1.44269504088896340736f; // fold 1/4 scale + log2(e)
}

typedef unsigned short u16;
typedef unsigned int u32;
typedef __attribute__((ext_vector_type(4))) float f32x4;
typedef __attribute__((ext_vector_type(8))) __bf16 bf16x8;
typedef __attribute__((ext_vector_type(4))) unsigned short u16x4;
typedef __attribute__((ext_vector_type(8))) unsigned short u16x8;
typedef __attribute__((ext_vector_type(4))) unsigned int u32x4;

__device__ __forceinline__ u16 f2bf(float f) {
    union { float f; unsigned u; } cv; cv.f = f;
    unsigned u = cv.u + 0x7fffu + ((cv.u >> 16) & 1u);
    return (u16)(u >> 16);
}

// packed bf16 pair via native casts (compiler emits v_cvt_pk_bf16_f32)
__device__ __forceinline__ u32 pkbf(float a, float b) {
    union { __bf16 h[2]; u32 u; } cv;
    cv.h[0] = (__bf16)a; cv.h[1] = (__bf16)b;
    return cv.u;
}

// DPP cross-lane (16-lane row) reductions — VALU pipe, no LDS
template <int CTRL>
__device__ __forceinline__ float dppf(float x) {
    return __int_as_float(__builtin_amdgcn_update_dpp(
        0, __float_as_int(x), CTRL, 0xf, 0xf, true));
}
__device__ __forceinline__ float red16_max(float x) {
    x = fmaxf(x, dppf<0xB1>(x));   // quad_perm(1,0,3,2)
    x = fmaxf(x, dppf<0x4E>(x));   // quad_perm(2,3,0,1)
    x = fmaxf(x, dppf<0x141>(x));  // row_half_mirror
    x = fmaxf(x, dppf<0x140>(x));  // row_mirror
    return x;
}
__device__ __forceinline__ float red16_add(float x) {
    x += dppf<0xB1>(x);
    x += dppf<0x4E>(x);
    x += dppf<0x141>(x);
    x += dppf<0x140>(x);
    return x;
}

__device__ __forceinline__ void gload16(const void* g, void* l) {
    __builtin_amdgcn_global_load_lds(
        (const __attribute__((address_space(1))) unsigned int*)g,
        (__attribute__((address_space(3))) unsigned int*)l, 16, 0, 0);
}

// ---------------------------------------------------------------------------
// f32 -> bf16 convert (vectorized: 4 floats / thread)
// ---------------------------------------------------------------------------
__global__ __launch_bounds__(256)
void cvt_bf16(const float* __restrict__ in, u16* __restrict__ out, int n4)
{
    int i = blockIdx.x * 256 + threadIdx.x;
    if (i >= n4) return;
    f32x4 v = ((const f32x4*)in)[i];
    u16x4 o;
#pragma unroll
    for (int j = 0; j < 4; ++j) o[j] = f2bf(v[j]);
    ((u16x4*)out)[i] = o;
}

// ---------------------------------------------------------------------------
// bf16 MFMA GEMM: C[M][1024] = A[M][1024] @ B[1024][1024]^T + bias
// 128x128 tile, BK=32, 256 thr (4 waves 2x2), wave tile 64x64 = 4x4 frags.
// mode 0: write f32 C.  mode 1: fused per-head Lorentz projection; write bf16
// to [b][h][l][64]; time := tsign*sqrt(1+ssq); whole head row * scale.
// ---------------------------------------------------------------------------
__global__ __launch_bounds__(256)
void gemm_bf16(const u16* __restrict__ A, const u16* __restrict__ B,
               const float* __restrict__ bias, void* __restrict__ Cout,
               int mode, float scale, float tsign)
{
    __shared__ u16 As[128 * 32];
    __shared__ u16 Bs[128 * 32];
    const int t = threadIdx.x;
    const int lane = t & 63, w = t >> 6;
    const int g = lane >> 4, c = lane & 15;
    const int wr = w >> 1, wc = w & 1;
    const int bm = blockIdx.y * 128, bn = blockIdx.x * 128;

    f32x4 acc[4][4];
    const f32x4 z4 = {0.f, 0.f, 0.f, 0.f};
#pragma unroll
    for (int i = 0; i < 4; ++i)
#pragma unroll
        for (int j = 0; j < 4; ++j) acc[i][j] = z4;

    for (int k0 = 0; k0 < Dn; k0 += 32) {
        __syncthreads();
#pragma unroll
        for (int s = 0; s < 2; ++s) {
            int ci = s * 256 + t;
            int r = ci >> 2, ks = (ci & 3) * 8;
            gload16(A + (size_t)(bm + r) * Dn + k0 + ks, &As[ci * 8]);
            gload16(B + (size_t)(bn + r) * Dn + k0 + ks, &Bs[ci * 8]);
        }
        __syncthreads();
        bf16x8 a[4], b[4];
#pragma unroll
        for (int mi = 0; mi < 4; ++mi)
            a[mi] = *(const bf16x8*)&As[(wr * 64 + mi * 16 + c) * 32 + g * 8];
#pragma unroll
        for (int ni = 0; ni < 4; ++ni)
            b[ni] = *(const bf16x8*)&Bs[(wc * 64 + ni * 16 + c) * 32 + g * 8];
#pragma unroll
        for (int mi = 0; mi < 4; ++mi)
#pragma unroll
            for (int ni = 0; ni < 4; ++ni)
                acc[mi][ni] = __builtin_amdgcn_mfma_f32_16x16x32_bf16(
                    a[mi], b[ni], acc[mi][ni], 0, 0, 0);
    }

    if (mode == 0) {
        float* Cf = (float*)Cout;
#pragma unroll
        for (int mi = 0; mi < 4; ++mi)
#pragma unroll
            for (int j = 0; j < 4; ++j) {
                size_t row = bm + wr * 64 + mi * 16 + g * 4 + j;
#pragma unroll
                for (int ni = 0; ni < 4; ++ni) {
                    int col = bn + wc * 64 + ni * 16 + c;
                    Cf[row * Dn + col] = acc[mi][ni][j] + bias[col];
                }
            }
    } else {
        u16* Ct = (u16*)Cout;
        const int hcb = bn + wc * 64;
        const int h = hcb >> 6;
#pragma unroll
        for (int mi = 0; mi < 4; ++mi)
#pragma unroll
            for (int j = 0; j < 4; ++j) {
                int row = bm + wr * 64 + mi * 16 + g * 4 + j;
                float zv[4];
#pragma unroll
                for (int ni = 0; ni < 4; ++ni)
                    zv[ni] = acc[mi][ni][j] + bias[hcb + ni * 16 + c];
                float loc = zv[0]*zv[0] + zv[1]*zv[1] + zv[2]*zv[2] + zv[3]*zv[3];
                if (c == 0) loc -= 2.f * zv[0] * zv[0];
#pragma unroll
                for (int off = 8; off; off >>= 1) loc += __shfl_xor(loc, off);
                float tval = sqrtf(1.f + loc);
                int bb = row >> 11, ll = row & 2047;
                u16* dst = Ct + (((size_t)bb * 16 + h) * Ln + ll) * 64;
#pragma unroll
                for (int ni = 0; ni < 4; ++ni) {
                    float val = (ni == 0 && c == 0) ? tsign * tval : zv[ni];
                    dst[ni * 16 + c] = f2bf(val * scale);
                }
            }
    }
}

// ---------------------------------------------------------------------------
// V transpose: [bh][l][64] -> [bh][d][Ln], with a within-64-chunk position
// permutation on l so attention's packed P writes line up:
//   k(pos) = (pos>>5)*32 + (pos&1)*16 + ((pos&31)>>1)
// ---------------------------------------------------------------------------
__global__ __launch_bounds__(256)
void transpose_v(const u16* __restrict__ vin, u16* __restrict__ vout)
{
    __shared__ u16 tile[64][72];          // pad: pitch 144B (16B-aligned, bank-spread)
    const int t = threadIdx.x;
    const int bh = blockIdx.x, lc = blockIdx.y;
    const u16* src = vin + ((size_t)bh * Ln + lc * 64) * 64;
#pragma unroll
    for (int p = 0; p < 2; ++p) {
        int si = p * 256 + t, r = si >> 3, s = si & 7;
        *(u16x8*)&tile[r][s * 8] = *(const u16x8*)(src + r * 64 + s * 8);
    }
    __syncthreads();
    const int d = t >> 2, pos0 = (t & 3) * 16;
    u16 buf[16];
#pragma unroll
    for (int i = 0; i < 16; ++i) {
        int pos = pos0 + i;
        int k = ((pos >> 5) << 5) + ((pos & 1) << 4) + ((pos & 31) >> 1);
        buf[i] = tile[k][d];
    }
    u16* dst = vout + ((size_t)bh * 64 + d) * Ln + lc * 64 + pos0;
    *(u16x8*)dst       = *(const u16x8*)&buf[0];
    *(u16x8*)(dst + 8) = *(const u16x8*)&buf[8];
}

// ---------------------------------------------------------------------------
// MFMA flash attention per (b,h). 256 thr (4 waves), 64 q-rows/block
// (16/wave), KV chunk 64. K [n][d] and V^T [d][pos] staged reg->LDS with XOR
// swizzle (conflict-free b128 r/w). P packed u32 writes, per-wave LDS.
// DPP reductions, exp2 softmax, defer-max. Epilogue fuses mu normalization.
// ---------------------------------------------------------------------------
__global__ __launch_bounds__(256)
void attn_mfma(const u16* __restrict__ qt, const u16* __restrict__ kt,
               const u16* __restrict__ vT, u16* __restrict__ cat)
{
    __shared__ u16 k_s[64 * 64];
    __shared__ u16 v_s[64 * 64];
    __shared__ u16 p_s[4 * 16 * 64];

    const int t = threadIdx.x;
    const int lane = t & 63, w = t >> 6;
    const int g = lane >> 4, c = lane & 15;
    const int bh = blockIdx.x;
    const int q0 = blockIdx.y * 64;
    const u16* Q = qt + (size_t)bh * Ln * 64;
    const u16* K = kt + (size_t)bh * Ln * 64;
    const u16* V = vT + (size_t)bh * 64 * Ln;

    // Q fragments in registers for the whole KV sweep (A-frag: row = c)
    bf16x8 qa[2];
#pragma unroll
    for (int kk = 0; kk < 2; ++kk)
        qa[kk] = *(const bf16x8*)(Q + (size_t)(q0 + w * 16 + c) * 64 + kk * 32 + g * 8);

    f32x4 o[4];
    float mrow[4], lrow[4];
    const f32x4 z4 = {0.f, 0.f, 0.f, 0.f};
#pragma unroll
    for (int di = 0; di < 4; ++di) o[di] = z4;
#pragma unroll
    for (int j = 0; j < 4; ++j) { mrow[j] = -1e30f; lrow[j] = 0.f; }

    u16* ps_w = p_s + w * 1024;
    u32x4 kr[2], vr[2];

    // prologue load (chunk 0)
#pragma unroll
    for (int s = 0; s < 2; ++s) {
        int seg = s * 256 + t, r = seg >> 3, sl = seg & 7;
        kr[s] = *(const u32x4*)(K + (size_t)r * 64 + sl * 8);
        vr[s] = *(const u32x4*)(V + (size_t)r * Ln + sl * 8);
    }

    for (int ch = 0; ch < Ln / 64; ++ch) {
        __syncthreads();                    // prior chunk's k_s/v_s reads done
#pragma unroll
        for (int s = 0; s < 2; ++s) {
            int seg = s * 256 + t, r = seg >> 3, sl = seg & 7;
            int bo = (sl * 16) ^ ((r & 7) << 4);
            *(u32x4*)&k_s[r * 64 + (bo >> 1)] = kr[s];
            *(u32x4*)&v_s[r * 64 + (bo >> 1)] = vr[s];
        }
        __syncthreads();                    // staged data visible
        if (ch + 1 < Ln / 64) {             // prefetch next chunk into regs
#pragma unroll
            for (int s = 0; s < 2; ++s) {
                int seg = s * 256 + t, r = seg >> 3, sl = seg & 7;
                kr[s] = *(const u32x4*)(K + (size_t)((ch + 1) * 64 + r) * 64 + sl * 8);
                vr[s] = *(const u32x4*)(V + (size_t)r * Ln + (ch + 1) * 64 + sl * 8);
            }
        }

        // ---- QK^T (8 MFMA) ----
        f32x4 sf[4];
#pragma unroll
        for (int ni = 0; ni < 4; ++ni) sf[ni] = z4;
#pragma unroll
        for (int kk = 0; kk < 2; ++kk)
#pragma unroll
            for (int ni = 0; ni < 4; ++ni) {
                int n = ni * 16 + c;
                bf16x8 kb = *(const bf16x8*)&k_s[n * 64 +
                    (((kk * 64 + g * 16) ^ ((n & 7) << 4)) >> 1)];
                sf[ni] = __builtin_amdgcn_mfma_f32_16x16x32_bf16(
                    qa[kk], kb, sf[ni], 0, 0, 0);
            }

        // ---- online softmax (DPP reduce, exp2, defer-max) ----
        float mx[4];
        int grow = 0;
#pragma unroll
        for (int j = 0; j < 4; ++j) {
            float m0 = fmaxf(fmaxf(sf[0][j], sf[1][j]), fmaxf(sf[2][j], sf[3][j]));
            mx[j] = red16_max(m0);
            grow |= (mx[j] > mrow[j] + 11.0f) ? 1 : 0;
        }
        if (__any(grow)) {
#pragma unroll
            for (int j = 0; j < 4; ++j) {
                float mnew = fmaxf(mrow[j], mx[j]);
                float scl = exp2f(mrow[j] - mnew);
                mrow[j] = mnew;
                lrow[j] *= scl;
#pragma unroll
                for (int di = 0; di < 4; ++di) o[di][j] *= scl;
            }
        }
#pragma unroll
        for (int j = 0; j < 4; ++j) {
            int ql = g * 4 + j;
            float p0 = exp2f(sf[0][j] - mrow[j]);
            float p1 = exp2f(sf[1][j] - mrow[j]);
            float p2 = exp2f(sf[2][j] - mrow[j]);
            float p3 = exp2f(sf[3][j] - mrow[j]);
            lrow[j] += red16_add(p0 + p1 + p2 + p3);
            int swz = (ql & 7) << 4;
            *(u32*)&ps_w[(ql * 128 + ((4 * c) ^ swz)) >> 1]      = pkbf(p0, p1);
            *(u32*)&ps_w[(ql * 128 + ((64 + 4 * c) ^ swz)) >> 1] = pkbf(p2, p3);
        }

        // ---- PV (8 MFMA); p_s is per-wave, same-wave DS order suffices ----
#pragma unroll
        for (int kk = 0; kk < 2; ++kk) {
            bf16x8 pa = *(const bf16x8*)&ps_w[(c * 128 +
                (((kk * 64 + g * 16)) ^ ((c & 7) << 4))) >> 1];
#pragma unroll
            for (int di = 0; di < 4; ++di) {
                int d = di * 16 + c;
                bf16x8 vb = *(const bf16x8*)&v_s[d * 64 +
                    (((kk * 64 + g * 16) ^ ((d & 7) << 4)) >> 1)];
                o[di] = __builtin_amdgcn_mfma_f32_16x16x32_bf16(
                    pa, vb, o[di], 0, 0, 0);
            }
        }
    }

    // ---- epilogue: mu = o/l, Lorentz normalize, write bf16 cat ----
    const int b = bh >> 4, h = bh & 15;
#pragma unroll
    for (int j = 0; j < 4; ++j) {
        float linv = 1.f / lrow[j];
        float mu[4];
#pragma unroll
        for (int di = 0; di < 4; ++di) mu[di] = o[di][j] * linv;
        float loc = mu[0]*mu[0] + mu[1]*mu[1] + mu[2]*mu[2] + mu[3]*mu[3];
        if (c == 0) loc -= 2.f * mu[0] * mu[0];
        loc = red16_add(loc);
        float rn = rsqrtf(fmaxf(fabsf(loc), 1e-6f));
        int row = q0 + w * 16 + g * 4 + j;
        u16* dst = cat + ((size_t)b * Ln + row) * Dn + h * 64;
#pragma unroll
        for (int di = 0; di < 4; ++di)
            dst[di * 16 + c] = f2bf(mu[di] * rn);
    }
}

// ---------------------------------------------------------------------------
// Full-row (D=1024) Lorentz projection on f32 output rows.
// ---------------------------------------------------------------------------
__global__ __launch_bounds__(256)
void lorentz_row_full(float* __restrict__ z)
{
    __shared__ float red[4];
    const int t = threadIdx.x;
    const size_t base = (size_t)blockIdx.x * Dn;
    float4 v = *(const float4*)&z[base + t * 4];
    if (t == 0) v.x = 0.f;
    float ssq = v.x * v.x + v.y * v.y + v.z * v.z + v.w * v.w;
#pragma unroll
    for (int off = 32; off; off >>= 1) ssq += __shfl_xor(ssq, off);
    if ((t & 63) == 0) red[t >> 6] = ssq;
    __syncthreads();
    if (t == 0) z[base] = sqrtf(1.0f + red[0] + red[1] + red[2] + red[3]);
}

// ---------------------------------------------------------------------------
extern "C" void kernel_launch(void* const* d_in, const int* in_sizes, int n_in,
                              void* d_out, int out_size, void* d_ws, size_t ws_size,
                              hipStream_t stream)
{
    const float* query = (const float*)d_in[0];
    const float* key_  = (const float*)d_in[1];
    const float* value = (const float*)d_in[2];
    const float* W_Q   = (const float*)d_in[3];
    const float* b_Q   = (const float*)d_in[4];
    const float* W_K   = (const float*)d_in[5];
    const float* b_K   = (const float*)d_in[6];
    const float* W_V   = (const float*)d_in[7];
    const float* b_V   = (const float*)d_in[8];
    const float* W_O   = (const float*)d_in[9];
    const float* b_O   = (const float*)d_in[10];

    u16* xq  = (u16*)d_ws;                     // bf16 inputs  [4096][1024]
    u16* xk  = xq  + (size_t)Mn * Dn;
    u16* xv  = xk  + (size_t)Mn * Dn;
    u16* wq  = xv  + (size_t)Mn * Dn;          // bf16 weights [1024][1024]
    u16* wk  = wq  + (size_t)Dn * Dn;
    u16* wv  = wk  + (size_t)Dn * Dn;
    u16* wo  = wv  + (size_t)Dn * Dn;
    u16* q_t = wo  + (size_t)Dn * Dn;          // bf16 [b][h][l][64]
    u16* k_t = q_t + (size_t)Mn * Dn;
    u16* v_T = k_t + (size_t)Mn * Dn;          // bf16 [b][h][64][Ln] (perm'd l)
    u16* cat = v_T + (size_t)Mn * Dn;          // bf16 [b][l][1024]
    u16* v_ln = xq;                            // reuse xq after Q GEMM

    const int n4x = Mn * Dn / 4, n4w = Dn * Dn / 4;
    cvt_bf16<<<n4x / 256, 256, 0, stream>>>(query, xq, n4x);
    cvt_bf16<<<n4x / 256, 256, 0, stream>>>(key_,  xk, n4x);
    cvt_bf16<<<n4x / 256, 256, 0, stream>>>(value, xv, n4x);
    cvt_bf16<<<n4w / 256, 256, 0, stream>>>(W_Q, wq, n4w);
    cvt_bf16<<<n4w / 256, 256, 0, stream>>>(W_K, wk, n4w);
    cvt_bf16<<<n4w / 256, 256, 0, stream>>>(W_V, wv, n4w);
    cvt_bf16<<<n4w / 256, 256, 0, stream>>>(W_O, wo, n4w);

    dim3 gg(Dn / 128, Mn / 128);               // (8, 32)
    // q: fold Lorentz metric (negate time) + 0.25 scale + log2e into storage
    gemm_bf16<<<gg, 256, 0, stream>>>(xq, wq, b_Q, q_t, 1, QSCALE, -1.f);
    gemm_bf16<<<gg, 256, 0, stream>>>(xk, wk, b_K, k_t, 1, 1.f, 1.f);
    gemm_bf16<<<gg, 256, 0, stream>>>(xv, wv, b_V, v_ln, 1, 1.f, 1.f);

    dim3 tg(32, Ln / 64);                      // (32, 32)
    transpose_v<<<tg, 256, 0, stream>>>(v_ln, v_T);

    dim3 ag(32, Ln / 64);                      // (32, 32) = 1024 blocks
    attn_mfma<<<ag, 256, 0, stream>>>(q_t, k_t, v_T, cat);

    gemm_bf16<<<gg, 256, 0, stream>>>(cat, wo, b_O, d_out, 0, 1.f, 1.f);
    lorentz_row_full<<<Mn, 256, 0, stream>>>((float*)d_out);
}

// Round 4
// 172.191 us; speedup vs baseline: 14.7435x; 1.3370x over previous
//
#include <hip/hip_runtime.h>
#include <math.h>

namespace {
constexpr int Ln = 2048;
constexpr int Dn = 1024;
constexpr int Mn = 4096;   // B*L
constexpr float QSCALE = 0.25f * 1.44269504088896340736f; // fold 1/4 scale + log2(e)
}

typedef unsigned short u16;
typedef unsigned int u32;
typedef __attribute__((ext_vector_type(4))) float f32x4;
typedef __attribute__((ext_vector_type(8))) __bf16 bf16x8;
typedef __attribute__((ext_vector_type(4))) unsigned short u16x4;
typedef __attribute__((ext_vector_type(8))) unsigned short u16x8;
typedef __attribute__((ext_vector_type(2))) unsigned int u32x2;
typedef __attribute__((ext_vector_type(4))) unsigned int u32x4;

__device__ __forceinline__ u16 f2bf(float f) {
    union { float f; unsigned u; } cv; cv.f = f;
    unsigned u = cv.u + 0x7fffu + ((cv.u >> 16) & 1u);
    return (u16)(u >> 16);
}

// packed bf16 pair (compiler emits v_cvt_pk_bf16_f32)
__device__ __forceinline__ u32 pkbf(float a, float b) {
    union { __bf16 h[2]; u32 u; } cv;
    cv.h[0] = (__bf16)a; cv.h[1] = (__bf16)b;
    return cv.u;
}

// DPP cross-lane (16-lane row) sum — VALU pipe, no LDS
template <int CTRL>
__device__ __forceinline__ float dppf(float x) {
    return __int_as_float(__builtin_amdgcn_update_dpp(
        0, __float_as_int(x), CTRL, 0xf, 0xf, true));
}
__device__ __forceinline__ float red16_add(float x) {
    x += dppf<0xB1>(x);    // quad_perm(1,0,3,2)
    x += dppf<0x4E>(x);    // quad_perm(2,3,0,1)
    x += dppf<0x141>(x);   // row_half_mirror
    x += dppf<0x140>(x);   // row_mirror
    return x;
}

__device__ __forceinline__ void gload16(const void* g, void* l) {
    __builtin_amdgcn_global_load_lds(
        (const __attribute__((address_space(1))) unsigned int*)g,
        (__attribute__((address_space(3))) unsigned int*)l, 16, 0, 0);
}

// ---------------------------------------------------------------------------
// f32 -> bf16 convert, up to 4 tensors per launch (blockIdx.y selects)
// ---------------------------------------------------------------------------
__global__ __launch_bounds__(256)
void cvt_bf16_multi(const float* __restrict__ i0, const float* __restrict__ i1,
                    const float* __restrict__ i2, const float* __restrict__ i3,
                    u16* __restrict__ o0, u16* __restrict__ o1,
                    u16* __restrict__ o2, u16* __restrict__ o3, int n4)
{
    const int z = blockIdx.y;
    const float* in = z == 0 ? i0 : (z == 1 ? i1 : (z == 2 ? i2 : i3));
    u16* out       = z == 0 ? o0 : (z == 1 ? o1 : (z == 2 ? o2 : o3));
    int i = blockIdx.x * 256 + threadIdx.x;
    if (i >= n4) return;
    f32x4 v = ((const f32x4*)in)[i];
    u16x4 o;
#pragma unroll
    for (int j = 0; j < 4; ++j) o[j] = f2bf(v[j]);
    ((u16x4*)out)[i] = o;
}

// ---------------------------------------------------------------------------
// bf16 MFMA GEMM body: C[M][1024] = A[M][1024] @ B[1024][1024]^T + bias
// 128x128 tile, BK=32, 256 thr (4 waves 2x2), wave tile 64x64 = 4x4 frags.
// mode 0: write f32 C.  mode 1: fused per-head Lorentz projection; write bf16
// to [b][h][l][64]; time := tsign*sqrt(1+ssq); whole head row * scale.
// ---------------------------------------------------------------------------
__device__ __forceinline__
void gemm_body(const u16* __restrict__ A, const u16* __restrict__ B,
               const float* __restrict__ bias, void* __restrict__ Cout,
               int mode, float scale, float tsign, u16* As, u16* Bs)
{
    const int t = threadIdx.x;
    const int lane = t & 63, w = t >> 6;
    const int g = lane >> 4, c = lane & 15;
    const int wr = w >> 1, wc = w & 1;
    const int bm = blockIdx.y * 128, bn = blockIdx.x * 128;

    f32x4 acc[4][4];
    const f32x4 z4 = {0.f, 0.f, 0.f, 0.f};
#pragma unroll
    for (int i = 0; i < 4; ++i)
#pragma unroll
        for (int j = 0; j < 4; ++j) acc[i][j] = z4;

    for (int k0 = 0; k0 < Dn; k0 += 32) {
        __syncthreads();
#pragma unroll
        for (int s = 0; s < 2; ++s) {
            int ci = s * 256 + t;
            int r = ci >> 2, ks = (ci & 3) * 8;
            gload16(A + (size_t)(bm + r) * Dn + k0 + ks, &As[ci * 8]);
            gload16(B + (size_t)(bn + r) * Dn + k0 + ks, &Bs[ci * 8]);
        }
        __syncthreads();
        bf16x8 a[4], b[4];
#pragma unroll
        for (int mi = 0; mi < 4; ++mi)
            a[mi] = *(const bf16x8*)&As[(wr * 64 + mi * 16 + c) * 32 + g * 8];
#pragma unroll
        for (int ni = 0; ni < 4; ++ni)
            b[ni] = *(const bf16x8*)&Bs[(wc * 64 + ni * 16 + c) * 32 + g * 8];
        __builtin_amdgcn_s_setprio(1);
#pragma unroll
        for (int mi = 0; mi < 4; ++mi)
#pragma unroll
            for (int ni = 0; ni < 4; ++ni)
                acc[mi][ni] = __builtin_amdgcn_mfma_f32_16x16x32_bf16(
                    a[mi], b[ni], acc[mi][ni], 0, 0, 0);
        __builtin_amdgcn_s_setprio(0);
    }

    if (mode == 0) {
        float* Cf = (float*)Cout;
#pragma unroll
        for (int mi = 0; mi < 4; ++mi)
#pragma unroll
            for (int j = 0; j < 4; ++j) {
                size_t row = bm + wr * 64 + mi * 16 + g * 4 + j;
#pragma unroll
                for (int ni = 0; ni < 4; ++ni) {
                    int col = bn + wc * 64 + ni * 16 + c;
                    Cf[row * Dn + col] = acc[mi][ni][j] + bias[col];
                }
            }
    } else {
        u16* Ct = (u16*)Cout;
        const int hcb = bn + wc * 64;
        const int h = hcb >> 6;
#pragma unroll
        for (int mi = 0; mi < 4; ++mi)
#pragma unroll
            for (int j = 0; j < 4; ++j) {
                int row = bm + wr * 64 + mi * 16 + g * 4 + j;
                float zv[4];
#pragma unroll
                for (int ni = 0; ni < 4; ++ni)
                    zv[ni] = acc[mi][ni][j] + bias[hcb + ni * 16 + c];
                float loc = zv[0]*zv[0] + zv[1]*zv[1] + zv[2]*zv[2] + zv[3]*zv[3];
                if (c == 0) loc -= 2.f * zv[0] * zv[0];
#pragma unroll
                for (int off = 8; off; off >>= 1) loc += __shfl_xor(loc, off);
                float tval = sqrtf(1.f + loc);
                int bb = row >> 11, ll = row & 2047;
                u16* dst = Ct + (((size_t)bb * 16 + h) * Ln + ll) * 64;
#pragma unroll
                for (int ni = 0; ni < 4; ++ni) {
                    float val = (ni == 0 && c == 0) ? tsign * tval : zv[ni];
                    dst[ni * 16 + c] = f2bf(val * scale);
                }
            }
    }
}

__global__ __launch_bounds__(256)
void gemm_bf16(const u16* __restrict__ A, const u16* __restrict__ B,
               const float* __restrict__ bias, void* __restrict__ Cout,
               int mode, float scale, float tsign)
{
    __shared__ u16 As[128 * 32];
    __shared__ u16 Bs[128 * 32];
    gemm_body(A, B, bias, Cout, mode, scale, tsign, As, Bs);
}

// Q/K/V GEMMs fused into one dispatch (blockIdx.z selects) -> 3 blocks/CU
__global__ __launch_bounds__(256)
void gemm_qkv(const u16* __restrict__ xq, const u16* __restrict__ xk,
              const u16* __restrict__ xv, const u16* __restrict__ wq,
              const u16* __restrict__ wk, const u16* __restrict__ wv,
              const float* __restrict__ bq, const float* __restrict__ bk,
              const float* __restrict__ bv,
              u16* __restrict__ oq, u16* __restrict__ ok, u16* __restrict__ ov)
{
    __shared__ u16 As[128 * 32];
    __shared__ u16 Bs[128 * 32];
    const int z = blockIdx.z;
    const u16* A = z == 0 ? xq : (z == 1 ? xk : xv);
    const u16* W = z == 0 ? wq : (z == 1 ? wk : wv);
    const float* bb = z == 0 ? bq : (z == 1 ? bk : bv);
    u16* O = z == 0 ? oq : (z == 1 ? ok : ov);
    gemm_body(A, W, bb, O, 1, z == 0 ? QSCALE : 1.f, z == 0 ? -1.f : 1.f, As, Bs);
}

// ---------------------------------------------------------------------------
// V transpose: [bh][l][64] -> [bh][d][Ln], with within-64-chunk position
// permutation on l matching attention's packed-b64 P writes:
//   n(pos) = (pos&3)*16 + (pos>>2)
// ---------------------------------------------------------------------------
__global__ __launch_bounds__(256)
void transpose_v(const u16* __restrict__ vin, u16* __restrict__ vout)
{
    __shared__ u16 tile[64][72];
    const int t = threadIdx.x;
    const int bh = blockIdx.x, lc = blockIdx.y;
    const u16* src = vin + ((size_t)bh * Ln + lc * 64) * 64;
#pragma unroll
    for (int p = 0; p < 2; ++p) {
        int si = p * 256 + t, r = si >> 3, s = si & 7;
        *(u16x8*)&tile[r][s * 8] = *(const u16x8*)(src + r * 64 + s * 8);
    }
    __syncthreads();
    const int d = t >> 2, pos0 = (t & 3) * 16;
    u16 buf[16];
#pragma unroll
    for (int i = 0; i < 16; ++i) {
        int pos = pos0 + i;
        int n = ((pos & 3) << 4) | (pos >> 2);
        buf[i] = tile[n][d];
    }
    u16* dst = vout + ((size_t)bh * 64 + d) * Ln + lc * 64 + pos0;
    *(u16x8*)dst       = *(const u16x8*)&buf[0];
    *(u16x8*)(dst + 8) = *(const u16x8*)&buf[8];
}

// ---------------------------------------------------------------------------
// MFMA flash attention per (b,h). 256 thr (4 waves), 64 q-rows/block.
// Fixed-max softmax (hyperboloid bound: scores <= 0 -> p = exp2(s), no
// running max, no rescale); deferred l-reduction (per-lane partials, one
// DPP reduce at epilogue). Double-buffered K/V staging, one barrier/chunk.
// P packed as one b64 write per row. Epilogue fuses mu normalization.
// ---------------------------------------------------------------------------
__global__ __launch_bounds__(256)
void attn_mfma(const u16* __restrict__ qt, const u16* __restrict__ kt,
               const u16* __restrict__ vT, u16* __restrict__ cat)
{
    __shared__ u16 k_s[2][64 * 64];
    __shared__ u16 v_s[2][64 * 64];
    __shared__ u16 p_s[4 * 16 * 64];

    const int t = threadIdx.x;
    const int lane = t & 63, w = t >> 6;
    const int g = lane >> 4, c = lane & 15;
    const int bh = blockIdx.x;
    const int q0 = blockIdx.y * 64;
    const u16* Q = qt + (size_t)bh * Ln * 64;
    const u16* K = kt + (size_t)bh * Ln * 64;
    const u16* V = vT + (size_t)bh * 64 * Ln;

    // Q fragments in registers for the whole KV sweep
    bf16x8 qa[2];
#pragma unroll
    for (int kk = 0; kk < 2; ++kk)
        qa[kk] = *(const bf16x8*)(Q + (size_t)(q0 + w * 16 + c) * 64 + kk * 32 + g * 8);

    f32x4 o[4];
    float lpart[4];
    const f32x4 z4 = {0.f, 0.f, 0.f, 0.f};
#pragma unroll
    for (int di = 0; di < 4; ++di) o[di] = z4;
#pragma unroll
    for (int j = 0; j < 4; ++j) lpart[j] = 0.f;

    u16* ps_w = p_s + w * 1024;
    const int sr = t >> 3, ssl = t & 7;          // staging row/slot (s=0)
    const int sr1 = (256 + t) >> 3, ssl1 = t & 7; // (s=1): r = 32 + sr

    u32x4 kr[2], vr[2];
    // prologue: load chunk 0
    kr[0] = *(const u32x4*)(K + (size_t)sr * 64 + ssl * 8);
    kr[1] = *(const u32x4*)(K + (size_t)sr1 * 64 + ssl1 * 8);
    vr[0] = *(const u32x4*)(V + (size_t)sr * Ln + ssl * 8);
    vr[1] = *(const u32x4*)(V + (size_t)sr1 * Ln + ssl1 * 8);

    constexpr int NC = Ln / 64;
    for (int ch = 0; ch < NC; ++ch) {
        u16* kb_s = k_s[ch & 1];
        u16* vb_s = v_s[ch & 1];
        {   // stage regs -> LDS (swizzled)
            int bo0 = (ssl * 16) ^ ((sr & 7) << 4);
            int bo1 = (ssl1 * 16) ^ ((sr1 & 7) << 4);
            *(u32x4*)&kb_s[sr  * 64 + (bo0 >> 1)] = kr[0];
            *(u32x4*)&kb_s[sr1 * 64 + (bo1 >> 1)] = kr[1];
            *(u32x4*)&vb_s[sr  * 64 + (bo0 >> 1)] = vr[0];
            *(u32x4*)&vb_s[sr1 * 64 + (bo1 >> 1)] = vr[1];
        }
        __syncthreads();
        if (ch + 1 < NC) {   // issue next-chunk loads early (hide under compute)
            kr[0] = *(const u32x4*)(K + (size_t)((ch + 1) * 64 + sr)  * 64 + ssl * 8);
            kr[1] = *(const u32x4*)(K + (size_t)((ch + 1) * 64 + sr1) * 64 + ssl1 * 8);
            vr[0] = *(const u32x4*)(V + (size_t)sr  * Ln + (ch + 1) * 64 + ssl * 8);
            vr[1] = *(const u32x4*)(V + (size_t)sr1 * Ln + (ch + 1) * 64 + ssl1 * 8);
        }

        // ---- QK^T (8 MFMA) ----
        f32x4 sf[4];
#pragma unroll
        for (int ni = 0; ni < 4; ++ni) sf[ni] = z4;
        __builtin_amdgcn_s_setprio(1);
#pragma unroll
        for (int kk = 0; kk < 2; ++kk)
#pragma unroll
            for (int ni = 0; ni < 4; ++ni) {
                int n = ni * 16 + c;
                bf16x8 kb = *(const bf16x8*)&kb_s[n * 64 +
                    (((kk * 64 + g * 16) ^ ((n & 7) << 4)) >> 1)];
                sf[ni] = __builtin_amdgcn_mfma_f32_16x16x32_bf16(
                    qa[kk], kb, sf[ni], 0, 0, 0);
            }
        __builtin_amdgcn_s_setprio(0);

        // ---- softmax, fixed max = 0 (scores <= 0 on hyperboloid) ----
#pragma unroll
        for (int j = 0; j < 4; ++j) {
            float p0 = exp2f(sf[0][j]);
            float p1 = exp2f(sf[1][j]);
            float p2 = exp2f(sf[2][j]);
            float p3 = exp2f(sf[3][j]);
            lpart[j] += (p0 + p1) + (p2 + p3);
            int ql = g * 4 + j;
            u32x2 pk = { pkbf(p0, p1), pkbf(p2, p3) };
            *(u32x2*)&ps_w[(ql * 128 + ((8 * c) ^ ((ql & 7) << 4))) >> 1] = pk;
        }

        // ---- PV (8 MFMA) ----
        __builtin_amdgcn_s_setprio(1);
#pragma unroll
        for (int kk = 0; kk < 2; ++kk) {
            bf16x8 pa = *(const bf16x8*)&ps_w[(c * 128 +
                ((kk * 64 + g * 16) ^ ((c & 7) << 4))) >> 1];
#pragma unroll
            for (int di = 0; di < 4; ++di) {
                int d = di * 16 + c;
                bf16x8 vb = *(const bf16x8*)&vb_s[d * 64 +
                    (((kk * 64 + g * 16) ^ ((d & 7) << 4)) >> 1)];
                o[di] = __builtin_amdgcn_mfma_f32_16x16x32_bf16(
                    pa, vb, o[di], 0, 0, 0);
            }
        }
        __builtin_amdgcn_s_setprio(0);
    }

    // ---- epilogue: l-reduce, mu = o/l, Lorentz normalize, write bf16 cat ----
    const int b = bh >> 4, h = bh & 15;
#pragma unroll
    for (int j = 0; j < 4; ++j) {
        float lrow = red16_add(lpart[j]);
        float linv = 1.f / lrow;
        float mu[4];
#pragma unroll
        for (int di = 0; di < 4; ++di) mu[di] = o[di][j] * linv;
        float loc = mu[0]*mu[0] + mu[1]*mu[1] + mu[2]*mu[2] + mu[3]*mu[3];
        if (c == 0) loc -= 2.f * mu[0] * mu[0];
        loc = red16_add(loc);
        float rn = rsqrtf(fmaxf(fabsf(loc), 1e-6f));
        int row = q0 + w * 16 + g * 4 + j;
        u16* dst = cat + ((size_t)b * Ln + row) * Dn + h * 64;
#pragma unroll
        for (int di = 0; di < 4; ++di)
            dst[di * 16 + c] = f2bf(mu[di] * rn);
    }
}

// ---------------------------------------------------------------------------
// Full-row (D=1024) Lorentz projection on f32 output rows.
// ---------------------------------------------------------------------------
__global__ __launch_bounds__(256)
void lorentz_row_full(float* __restrict__ z)
{
    __shared__ float red[4];
    const int t = threadIdx.x;
    const size_t base = (size_t)blockIdx.x * Dn;
    float4 v = *(const float4*)&z[base + t * 4];
    if (t == 0) v.x = 0.f;
    float ssq = v.x * v.x + v.y * v.y + v.z * v.z + v.w * v.w;
#pragma unroll
    for (int off = 32; off; off >>= 1) ssq += __shfl_xor(ssq, off);
    if ((t & 63) == 0) red[t >> 6] = ssq;
    __syncthreads();
    if (t == 0) z[base] = sqrtf(1.0f + red[0] + red[1] + red[2] + red[3]);
}

// ---------------------------------------------------------------------------
extern "C" void kernel_launch(void* const* d_in, const int* in_sizes, int n_in,
                              void* d_out, int out_size, void* d_ws, size_t ws_size,
                              hipStream_t stream)
{
    const float* query = (const float*)d_in[0];
    const float* key_  = (const float*)d_in[1];
    const float* value = (const float*)d_in[2];
    const float* W_Q   = (const float*)d_in[3];
    const float* b_Q   = (const float*)d_in[4];
    const float* W_K   = (const float*)d_in[5];
    const float* b_K   = (const float*)d_in[6];
    const float* W_V   = (const float*)d_in[7];
    const float* b_V   = (const float*)d_in[8];
    const float* W_O   = (const float*)d_in[9];
    const float* b_O   = (const float*)d_in[10];

    u16* xq  = (u16*)d_ws;                     // bf16 inputs  [4096][1024]
    u16* xk  = xq  + (size_t)Mn * Dn;
    u16* xv  = xk  + (size_t)Mn * Dn;
    u16* wq  = xv  + (size_t)Mn * Dn;          // bf16 weights [1024][1024]
    u16* wk  = wq  + (size_t)Dn * Dn;
    u16* wv  = wk  + (size_t)Dn * Dn;
    u16* wo  = wv  + (size_t)Dn * Dn;
    u16* q_t = wo  + (size_t)Dn * Dn;          // bf16 [b][h][l][64]
    u16* k_t = q_t + (size_t)Mn * Dn;
    u16* v_T = k_t + (size_t)Mn * Dn;          // bf16 [b][h][64][Ln] (perm'd l)
    u16* cat = v_T + (size_t)Mn * Dn;          // bf16 [b][l][1024]; also v GEMM out

    const int n4x = Mn * Dn / 4, n4w = Dn * Dn / 4;
    dim3 c3(n4x / 256, 3), c4(n4w / 256, 4);
    cvt_bf16_multi<<<c3, 256, 0, stream>>>(query, key_, value, query,
                                           xq, xk, xv, xq, n4x);
    cvt_bf16_multi<<<c4, 256, 0, stream>>>(W_Q, W_K, W_V, W_O,
                                           wq, wk, wv, wo, n4w);

    // fused Q/K/V projections; V output goes to (currently dead) cat buffer
    dim3 gq(Dn / 128, Mn / 128, 3);            // (8, 32, 3) = 768 blocks
    gemm_qkv<<<gq, 256, 0, stream>>>(xq, xk, xv, wq, wk, wv,
                                     b_Q, b_K, b_V, q_t, k_t, cat);

    dim3 tg(32, Ln / 64);                      // (32, 32)
    transpose_v<<<tg, 256, 0, stream>>>(cat, v_T);

    dim3 ag(32, Ln / 64);                      // (32, 32) = 1024 blocks
    attn_mfma<<<ag, 256, 0, stream>>>(q_t, k_t, v_T, cat);

    dim3 gg(Dn / 128, Mn / 128);               // (8, 32)
    gemm_bf16<<<gg, 256, 0, stream>>>(cat, wo, b_O, d_out, 0, 1.f, 1.f);
    lorentz_row_full<<<Mn, 256, 0, stream>>>((float*)d_out);
}

// Round 5
// 160.786 us; speedup vs baseline: 15.7893x; 1.0709x over previous
//
#include <hip/hip_runtime.h>
#include <math.h>

namespace {
constexpr int Ln = 2048;
constexpr int Dn = 1024;
constexpr int Mn = 4096;   // B*L
constexpr float QSCALE = 0.25f * 1.44269504088896340736f; // 2/sqrt(64) * log2(e)
}

typedef unsigned short u16;
typedef unsigned int u32;
typedef __attribute__((ext_vector_type(4))) float f32x4;
typedef __attribute__((ext_vector_type(8))) __bf16 bf16x8;
typedef __attribute__((ext_vector_type(4))) unsigned short u16x4;
typedef __attribute__((ext_vector_type(8))) unsigned short u16x8;
typedef __attribute__((ext_vector_type(2))) unsigned int u32x2;

// ============================================================================
// LAYOUT CONVENTIONS (write-side must match read-side):
// * bf16 matrices staged into LDS by global_load_lds are stored in global
//   PRE-SWIZZLED: within each 64-element (128B) k-slice of a row l, the
//   16B block b is stored at position b ^ (l&7).  Readers of an LDS tile
//   apply the same XOR with the local row (tiles are 8-row aligned).
// * Q/K projections store head features in SLOT order s = 4*(d&15) + (d>>4)
//   (so d = ni*16+c lands at slot 4c+ni -> packed b64 epilogue stores).
//   Q and K share the permutation => dot products unchanged.  V is stored
//   the same way; transpose_v un-permutes.  cat (attn output) uses the same
//   slot order per head, compensated by permuting W_O's input columns.
// * v_T ([bh][d][2048]) stores, within each 64-pos chunk, position-slot cp
//   holding seq n(cp) = (cp&3)*16 + (cp>>2), matching the P-matrix packing.
// ============================================================================

__device__ __forceinline__ u16 f2bf(float f) {
    union { float f; unsigned u; } cv; cv.f = f;
    unsigned u = cv.u + 0x7fffu + ((cv.u >> 16) & 1u);
    return (u16)(u >> 16);
}

__device__ __forceinline__ u32 pkbf(float a, float b) {
    union { __bf16 h[2]; u32 u; } cv;
    cv.h[0] = (__bf16)a; cv.h[1] = (__bf16)b;
    return cv.u;
}

// DPP cross-lane (16-lane row) sum — VALU pipe, no LDS
template <int CTRL>
__device__ __forceinline__ float dppf(float x) {
    return __int_as_float(__builtin_amdgcn_update_dpp(
        0, __float_as_int(x), CTRL, 0xf, 0xf, true));
}
__device__ __forceinline__ float red16_add(float x) {
    x += dppf<0xB1>(x);    // quad_perm(1,0,3,2)
    x += dppf<0x4E>(x);    // quad_perm(2,3,0,1)
    x += dppf<0x141>(x);   // row_half_mirror
    x += dppf<0x140>(x);   // row_mirror
    return x;
}

__device__ __forceinline__ void gload16(const void* g, void* l) {
    __builtin_amdgcn_global_load_lds(
        (const __attribute__((address_space(1))) unsigned int*)g,
        (__attribute__((address_space(3))) unsigned int*)l, 16, 0, 0);
}

// ---------------------------------------------------------------------------
// f32 -> bf16 convert of the 3 inputs, swizzled global layout (rows of 1024).
// ---------------------------------------------------------------------------
__global__ __launch_bounds__(256)
void cvt_in3(const float* __restrict__ i0, const float* __restrict__ i1,
             const float* __restrict__ i2,
             u16* __restrict__ o0, u16* __restrict__ o1, u16* __restrict__ o2)
{
    const int z = blockIdx.y;
    const float* in = z == 0 ? i0 : (z == 1 ? i1 : i2);
    u16* out       = z == 0 ? o0 : (z == 1 ? o1 : o2);
    int i = blockIdx.x * 256 + threadIdx.x;        // group of 4 elements
    f32x4 v = ((const f32x4*)in)[i];
    u16x4 o;
#pragma unroll
    for (int j = 0; j < 4; ++j) o[j] = f2bf(v[j]);
    int l = i >> 8;                // row
    int e = (i & 255) * 4;         // element within row
    int idx = l * 1024 + (e & ~63) + (((((e >> 3) & 7) ^ (l & 7))) << 3) + (e & 7);
    *(u16x4*)&out[idx] = o;
}

// ---------------------------------------------------------------------------
// Weights cvt: wq/wk/wv plain swizzle; wo (z==3) also permutes input columns
// to cat's per-head slot order.
// ---------------------------------------------------------------------------
__global__ __launch_bounds__(256)
void cvt_w(const float* __restrict__ w0, const float* __restrict__ w1,
           const float* __restrict__ w2, const float* __restrict__ w3,
           u16* __restrict__ q0, u16* __restrict__ q1,
           u16* __restrict__ q2, u16* __restrict__ q3)
{
    const int z = blockIdx.y;
    int i = blockIdx.x * 256 + threadIdx.x;
    if (z < 3) {
        const float* in = z == 0 ? w0 : (z == 1 ? w1 : w2);
        u16* out       = z == 0 ? q0 : (z == 1 ? q1 : q2);
        f32x4 v = ((const f32x4*)in)[i];
        u16x4 o;
#pragma unroll
        for (int j = 0; j < 4; ++j) o[j] = f2bf(v[j]);
        int l = i >> 8;
        int e = (i & 255) * 4;
        int idx = l * 1024 + (e & ~63) + (((((e >> 3) & 7) ^ (l & 7))) << 3) + (e & 7);
        *(u16x4*)&out[idx] = o;
    } else {
        int o  = i >> 8;             // output row of W_O (natural)
        int s0 = (i & 255) * 4;      // out column-slot base
        int h = s0 >> 6, sl = s0 & 63, a = sl >> 2;
        const float* src = w3 + (size_t)o * 1024 + h * 64;
        // slot s0+j holds input feature h*64 + j*16 + a
        u16x4 ov = { f2bf(src[a]), f2bf(src[16 + a]),
                     f2bf(src[32 + a]), f2bf(src[48 + a]) };
        int idx = o * 1024 + h * 64 + (((sl >> 3) ^ (o & 7)) << 3) + (sl & 7);
        *(u16x4*)&q3[idx] = ov;
    }
}

// ---------------------------------------------------------------------------
// Q/K/V projection GEMM + fused per-head Lorentz projection.
// 128x128 tile, BK=64, 256 thr (4 waves 2x2).  Output bf16 [b][h][l][64slots],
// slot-permuted + byte-swizzled, packed b64 stores.
// ---------------------------------------------------------------------------
__device__ __forceinline__
void gemm_proj_body(const u16* __restrict__ A, const u16* __restrict__ W,
                    const float* __restrict__ bias, u16* __restrict__ Ct,
                    float scale, float tsign, u16* As, u16* Bs)
{
    const int t = threadIdx.x;
    const int lane = t & 63, w = t >> 6;
    const int g = lane >> 4, c = lane & 15;
    const int wr = w >> 1, wc = w & 1;
    const int bm = blockIdx.y * 128, bn = blockIdx.x * 128;

    f32x4 acc[4][4];
    const f32x4 z4 = {0.f, 0.f, 0.f, 0.f};
#pragma unroll
    for (int i = 0; i < 4; ++i)
#pragma unroll
        for (int j = 0; j < 4; ++j) acc[i][j] = z4;

    for (int k0 = 0; k0 < Dn; k0 += 64) {
        __syncthreads();
#pragma unroll
        for (int p = 0; p < 4; ++p) {
            int ci = p * 256 + t;
            int r = ci >> 3, bq = ci & 7;
            gload16(A + (size_t)(bm + r) * Dn + k0 + bq * 8, &As[ci * 8]);
            gload16(W + (size_t)(bn + r) * Dn + k0 + bq * 8, &Bs[ci * 8]);
        }
        __syncthreads();
#pragma unroll
        for (int kk = 0; kk < 2; ++kk) {
            bf16x8 a[4], b[4];
#pragma unroll
            for (int mi = 0; mi < 4; ++mi)
                a[mi] = *(const bf16x8*)&As[(wr * 64 + mi * 16 + c) * 64 +
                                            (((kk * 4 + g) ^ (c & 7)) << 3)];
#pragma unroll
            for (int ni = 0; ni < 4; ++ni)
                b[ni] = *(const bf16x8*)&Bs[(wc * 64 + ni * 16 + c) * 64 +
                                            (((kk * 4 + g) ^ (c & 7)) << 3)];
            __builtin_amdgcn_s_setprio(1);
#pragma unroll
            for (int mi = 0; mi < 4; ++mi)
#pragma unroll
                for (int ni = 0; ni < 4; ++ni)
                    acc[mi][ni] = __builtin_amdgcn_mfma_f32_16x16x32_bf16(
                        a[mi], b[ni], acc[mi][ni], 0, 0, 0);
            __builtin_amdgcn_s_setprio(0);
        }
    }

    const int hcb = bn + wc * 64;
    const int h = hcb >> 6;
#pragma unroll
    for (int mi = 0; mi < 4; ++mi)
#pragma unroll
        for (int j = 0; j < 4; ++j) {
            int ll = bm + wr * 64 + mi * 16 + g * 4 + j;
            float zv[4];
#pragma unroll
            for (int ni = 0; ni < 4; ++ni)
                zv[ni] = acc[mi][ni][j] + bias[hcb + ni * 16 + c];
            float loc = zv[0]*zv[0] + zv[1]*zv[1] + zv[2]*zv[2] + zv[3]*zv[3];
            if (c == 0) loc -= zv[0] * zv[0];     // z0 is DISCARDED (once!)
            loc = red16_add(loc);                 // = sum of space^2
            float tval = sqrtf(1.f + loc);
            float v0 = (c == 0) ? tsign * tval : zv[0];
            int bb = ll >> 11, l2 = ll & 2047;
            u16* dst = Ct + (((size_t)bb * 16 + h) * Ln + l2) * 64;
            u16x4 pkv = { f2bf(v0 * scale), f2bf(zv[1] * scale),
                          f2bf(zv[2] * scale), f2bf(zv[3] * scale) };
            *(u16x4*)&dst[(4 * c) ^ ((ll & 7) << 3)] = pkv;
        }
}

__global__ __launch_bounds__(256)
void gemm_qkv(const u16* __restrict__ xq, const u16* __restrict__ xk,
              const u16* __restrict__ xv, const u16* __restrict__ wq,
              const u16* __restrict__ wk, const u16* __restrict__ wv,
              const float* __restrict__ bq, const float* __restrict__ bk,
              const float* __restrict__ bv,
              u16* __restrict__ oq, u16* __restrict__ ok, u16* __restrict__ ov)
{
    __shared__ u16 As[128 * 64];
    __shared__ u16 Bs[128 * 64];
    const int z = blockIdx.z;
    const u16* A = z == 0 ? xq : (z == 1 ? xk : xv);
    const u16* W = z == 0 ? wq : (z == 1 ? wk : wv);
    const float* bb = z == 0 ? bq : (z == 1 ? bk : bv);
    u16* O = z == 0 ? oq : (z == 1 ? ok : ov);
    gemm_proj_body(A, W, bb, O, z == 0 ? QSCALE : 1.f, z == 0 ? -1.f : 1.f, As, Bs);
}

// ---------------------------------------------------------------------------
// V transpose: [bh][l][64 slots,swz] -> v_T [bh][d][2048] with per-chunk
// pos-slot order n(cp) = (cp&3)*16 + (cp>>2), byte-swizzled per (d&7).
// ---------------------------------------------------------------------------
__global__ __launch_bounds__(256)
void transpose_v(const u16* __restrict__ vin, u16* __restrict__ vout)
{
    __shared__ u16 raw[64 * 64];     // straight copy of the swizzled tile
    const int t = threadIdx.x;
    const int bh = blockIdx.x, lc = blockIdx.y;
    const u16* src = vin + ((size_t)bh * Ln + lc * 64) * 64;
#pragma unroll
    for (int p = 0; p < 2; ++p) {
        int ci = p * 256 + t;
        *(u16x8*)&raw[ci * 8] = *(const u16x8*)(src + ci * 8);
    }
    __syncthreads();
    const int d = t >> 2, cp0 = (t & 3) * 16;
    const int s = ((d & 15) << 2) | (d >> 4);   // slot of true feature d
    u16 buf[16];
#pragma unroll
    for (int i = 0; i < 16; ++i) {
        int cp = cp0 + i;
        int n = ((cp & 3) << 4) | (cp >> 2);    // seq within chunk
        buf[i] = raw[n * 64 + ((((s >> 3) ^ (n & 7)) << 3) | (s & 7))];
    }
    u16* dst = vout + ((size_t)bh * 64 + d) * Ln + lc * 64;
    int b0 = cp0 >> 3;
    *(u16x8*)&dst[((b0 ^ (d & 7)) << 3)]       = *(const u16x8*)&buf[0];
    *(u16x8*)&dst[(((b0 + 1) ^ (d & 7)) << 3)] = *(const u16x8*)&buf[8];
}

// ---------------------------------------------------------------------------
// MFMA flash attention per (b,h).  4 waves x 32 q-rows = 128 q/block.
// K/V staged direct global->LDS (pre-swizzled source), double-buffered,
// one barrier per 64-KV chunk.  Fixed-max softmax (scores<=0), no
// denominator (mu/||mu|| is scale-invariant).  Epilogue: Lorentz normalize,
// packed b64 slot-stores into cat (swizzled for O-GEMM staging).
// ---------------------------------------------------------------------------
__global__ __launch_bounds__(256)
void attn_mfma(const u16* __restrict__ qt, const u16* __restrict__ kt,
               const u16* __restrict__ vT, u16* __restrict__ cat)
{
    __shared__ u16 k_s[2][64 * 64];
    __shared__ u16 v_s[2][64 * 64];
    __shared__ u16 p_s[4][32 * 64];

    const int t = threadIdx.x;
    const int lane = t & 63, w = t >> 6;
    const int g = lane >> 4, c = lane & 15;
    const int bh = blockIdx.x;
    const int q0 = blockIdx.y * 128;
    const u16* Q = qt + (size_t)bh * Ln * 64;
    const u16* K = kt + (size_t)bh * Ln * 64;
    const u16* V = vT + (size_t)bh * 64 * (size_t)Ln;

    // Q fragments (2 row-frags x 2 k-halves) in registers for the whole sweep
    bf16x8 qa[2][2];
#pragma unroll
    for (int mi = 0; mi < 2; ++mi)
#pragma unroll
        for (int kk = 0; kk < 2; ++kk) {
            int row = q0 + w * 32 + mi * 16 + c;
            qa[mi][kk] = *(const bf16x8*)(Q + (size_t)row * 64 +
                                          (((kk * 4 + g) ^ (c & 7)) << 3));
        }

    f32x4 o[2][4];
    const f32x4 z4 = {0.f, 0.f, 0.f, 0.f};
#pragma unroll
    for (int mi = 0; mi < 2; ++mi)
#pragma unroll
        for (int di = 0; di < 4; ++di) o[mi][di] = z4;

    const int cr = t >> 3, cb = t & 7;    // staging: row piece / 16B block

    // prologue: stage chunk 0 into buffer 0
#pragma unroll
    for (int p = 0; p < 2; ++p) {
        int r = p * 32 + cr;
        gload16(K + (size_t)r * 64 + cb * 8, &k_s[0][(p * 256 + t) * 8]);
        gload16(V + (size_t)r * Ln + cb * 8, &v_s[0][(p * 256 + t) * 8]);
    }

    constexpr int NC = Ln / 64;
    for (int ch = 0; ch < NC; ++ch) {
        const int cur = ch & 1;
        __syncthreads();   // staged chunk ch visible (drains gloads), prior reads done
        if (ch + 1 < NC) { // issue next-chunk staging; lands by next barrier
#pragma unroll
            for (int p = 0; p < 2; ++p) {
                int r = p * 32 + cr;
                gload16(K + (size_t)((ch + 1) * 64 + r) * 64 + cb * 8,
                        &k_s[cur ^ 1][(p * 256 + t) * 8]);
                gload16(V + (size_t)r * Ln + (ch + 1) * 64 + cb * 8,
                        &v_s[cur ^ 1][(p * 256 + t) * 8]);
            }
        }
        const u16* ks = k_s[cur];
        const u16* vs = v_s[cur];

        // ---- QK^T (16 MFMA) ----
        f32x4 sf[2][4];
#pragma unroll
        for (int mi = 0; mi < 2; ++mi)
#pragma unroll
            for (int ni = 0; ni < 4; ++ni) sf[mi][ni] = z4;
        __builtin_amdgcn_s_setprio(1);
#pragma unroll
        for (int kk = 0; kk < 2; ++kk) {
            bf16x8 kb[4];
#pragma unroll
            for (int ni = 0; ni < 4; ++ni) {
                int n = ni * 16 + c;
                kb[ni] = *(const bf16x8*)&ks[n * 64 +
                    (((kk * 64 + g * 16) ^ ((c & 7) << 4)) >> 1)];
            }
#pragma unroll
            for (int mi = 0; mi < 2; ++mi)
#pragma unroll
                for (int ni = 0; ni < 4; ++ni)
                    sf[mi][ni] = __builtin_amdgcn_mfma_f32_16x16x32_bf16(
                        qa[mi][kk], kb[ni], sf[mi][ni], 0, 0, 0);
        }
        __builtin_amdgcn_s_setprio(0);

        // ---- softmax numerator only, fixed max = 0 ----
        u16* pw = p_s[w];
#pragma unroll
        for (int mi = 0; mi < 2; ++mi)
#pragma unroll
            for (int j = 0; j < 4; ++j) {
                float p0 = exp2f(sf[mi][0][j]);
                float p1 = exp2f(sf[mi][1][j]);
                float p2 = exp2f(sf[mi][2][j]);
                float p3 = exp2f(sf[mi][3][j]);
                int ql = mi * 16 + g * 4 + j;
                u32x2 pk = { pkbf(p0, p1), pkbf(p2, p3) };
                *(u32x2*)&pw[ql * 64 + ((4 * c) ^ (((g * 4 + j) & 7) << 3))] = pk;
            }

        // ---- PV (16 MFMA) ----
        __builtin_amdgcn_s_setprio(1);
#pragma unroll
        for (int kk = 0; kk < 2; ++kk) {
            bf16x8 pa[2];
#pragma unroll
            for (int mi = 0; mi < 2; ++mi)
                pa[mi] = *(const bf16x8*)&pw[(mi * 16 + c) * 64 +
                    (((kk * 64 + g * 16) ^ ((c & 7) << 4)) >> 1)];
#pragma unroll
            for (int di = 0; di < 4; ++di) {
                int d = di * 16 + c;
                bf16x8 vb = *(const bf16x8*)&vs[d * 64 +
                    (((kk * 64 + g * 16) ^ ((c & 7) << 4)) >> 1)];
#pragma unroll
                for (int mi = 0; mi < 2; ++mi)
                    o[mi][di] = __builtin_amdgcn_mfma_f32_16x16x32_bf16(
                        pa[mi], vb, o[mi][di], 0, 0, 0);
            }
        }
        __builtin_amdgcn_s_setprio(0);
    }

    // ---- epilogue: Lorentz normalize o (scale-invariant), write cat ----
    const int b = bh >> 4, h = bh & 15;
#pragma unroll
    for (int mi = 0; mi < 2; ++mi)
#pragma unroll
        for (int j = 0; j < 4; ++j) {
            float mu[4];
#pragma unroll
            for (int di = 0; di < 4; ++di) mu[di] = o[mi][di][j];
            float loc = mu[0]*mu[0] + mu[1]*mu[1] + mu[2]*mu[2] + mu[3]*mu[3];
            if (c == 0) loc -= 2.f * mu[0] * mu[0];   // Lorentz inner <o,o>
            loc = red16_add(loc);
            float rn = rsqrtf(fmaxf(fabsf(loc), 1e-6f));
            int row = q0 + w * 32 + mi * 16 + g * 4 + j;
            u16* dst = cat + ((size_t)b * Ln + row) * Dn + h * 64;
            u16x4 pkv = { f2bf(mu[0] * rn), f2bf(mu[1] * rn),
                          f2bf(mu[2] * rn), f2bf(mu[3] * rn) };
            *(u16x4*)&dst[(4 * c) ^ ((row & 7) << 3)] = pkv;
        }
}

// ---------------------------------------------------------------------------
// Output GEMM: out[4096][1024] = cat @ wo^T + b_O (f32 out).
// 64x128 tile, BK=64, 512 blocks (2/CU).
// ---------------------------------------------------------------------------
__global__ __launch_bounds__(256)
void gemm_o(const u16* __restrict__ A, const u16* __restrict__ B,
            const float* __restrict__ bias, float* __restrict__ C)
{
    __shared__ u16 As[64 * 64];
    __shared__ u16 Bs[128 * 64];
    const int t = threadIdx.x;
    const int lane = t & 63, w = t >> 6;
    const int g = lane >> 4, c = lane & 15;
    const int wr = w >> 1, wc = w & 1;
    const int bm = blockIdx.y * 64, bn = blockIdx.x * 128;

    f32x4 acc[2][4];
    const f32x4 z4 = {0.f, 0.f, 0.f, 0.f};
#pragma unroll
    for (int i = 0; i < 2; ++i)
#pragma unroll
        for (int j = 0; j < 4; ++j) acc[i][j] = z4;

    for (int k0 = 0; k0 < Dn; k0 += 64) {
        __syncthreads();
#pragma unroll
        for (int p = 0; p < 2; ++p) {
            int ci = p * 256 + t;
            gload16(A + (size_t)(bm + (ci >> 3)) * Dn + k0 + (ci & 7) * 8,
                    &As[ci * 8]);
        }
#pragma unroll
        for (int p = 0; p < 4; ++p) {
            int ci = p * 256 + t;
            gload16(B + (size_t)(bn + (ci >> 3)) * Dn + k0 + (ci & 7) * 8,
                    &Bs[ci * 8]);
        }
        __syncthreads();
#pragma unroll
        for (int kk = 0; kk < 2; ++kk) {
            bf16x8 a[2], b[4];
#pragma unroll
            for (int mi = 0; mi < 2; ++mi)
                a[mi] = *(const bf16x8*)&As[(wr * 32 + mi * 16 + c) * 64 +
                                            (((kk * 4 + g) ^ (c & 7)) << 3)];
#pragma unroll
            for (int ni = 0; ni < 4; ++ni)
                b[ni] = *(const bf16x8*)&Bs[(wc * 64 + ni * 16 + c) * 64 +
                                            (((kk * 4 + g) ^ (c & 7)) << 3)];
            __builtin_amdgcn_s_setprio(1);
#pragma unroll
            for (int mi = 0; mi < 2; ++mi)
#pragma unroll
                for (int ni = 0; ni < 4; ++ni)
                    acc[mi][ni] = __builtin_amdgcn_mfma_f32_16x16x32_bf16(
                        a[mi], b[ni], acc[mi][ni], 0, 0, 0);
            __builtin_amdgcn_s_setprio(0);
        }
    }

#pragma unroll
    for (int mi = 0; mi < 2; ++mi)
#pragma unroll
        for (int j = 0; j < 4; ++j) {
            size_t row = bm + wr * 32 + mi * 16 + g * 4 + j;
#pragma unroll
            for (int ni = 0; ni < 4; ++ni) {
                int col = bn + wc * 64 + ni * 16 + c;
                C[row * Dn + col] = acc[mi][ni][j] + bias[col];
            }
        }
}

// ---------------------------------------------------------------------------
// Full-row (D=1024) Lorentz projection on f32 output rows.
// ---------------------------------------------------------------------------
__global__ __launch_bounds__(256)
void lorentz_row_full(float* __restrict__ z)
{
    __shared__ float red[4];
    const int t = threadIdx.x;
    const size_t base = (size_t)blockIdx.x * Dn;
    float4 v = *(const float4*)&z[base + t * 4];
    if (t == 0) v.x = 0.f;
    float ssq = v.x * v.x + v.y * v.y + v.z * v.z + v.w * v.w;
#pragma unroll
    for (int off = 32; off; off >>= 1) ssq += __shfl_xor(ssq, off);
    if ((t & 63) == 0) red[t >> 6] = ssq;
    __syncthreads();
    if (t == 0) z[base] = sqrtf(1.0f + red[0] + red[1] + red[2] + red[3]);
}

// ---------------------------------------------------------------------------
extern "C" void kernel_launch(void* const* d_in, const int* in_sizes, int n_in,
                              void* d_out, int out_size, void* d_ws, size_t ws_size,
                              hipStream_t stream)
{
    const float* query = (const float*)d_in[0];
    const float* key_  = (const float*)d_in[1];
    const float* value = (const float*)d_in[2];
    const float* W_Q   = (const float*)d_in[3];
    const float* b_Q   = (const float*)d_in[4];
    const float* W_K   = (const float*)d_in[5];
    const float* b_K   = (const float*)d_in[6];
    const float* W_V   = (const float*)d_in[7];
    const float* b_V   = (const float*)d_in[8];
    const float* W_O   = (const float*)d_in[9];
    const float* b_O   = (const float*)d_in[10];

    u16* xq   = (u16*)d_ws;                    // bf16 inputs (swz) [4096][1024]
    u16* xk   = xq  + (size_t)Mn * Dn;
    u16* xv   = xk  + (size_t)Mn * Dn;
    u16* wq   = xv  + (size_t)Mn * Dn;         // bf16 weights (swz) [1024][1024]
    u16* wk   = wq  + (size_t)Dn * Dn;
    u16* wv   = wk  + (size_t)Dn * Dn;
    u16* wo   = wv  + (size_t)Dn * Dn;         // + column slot-perm
    u16* q_t  = wo  + (size_t)Dn * Dn;         // bf16 [b][h][l][64slots]
    u16* k_t  = q_t + (size_t)Mn * Dn;
    u16* v_ln = k_t + (size_t)Mn * Dn;         // V projection, [b][h][l][64slots]
    u16* v_T  = xv;                            // alias: xv dead after gemm_qkv
    u16* cat  = xk;                            // alias: xk dead after gemm_qkv

    dim3 ci(Mn * Dn / 1024, 3);                // (4096, 3)
    cvt_in3<<<ci, 256, 0, stream>>>(query, key_, value, xq, xk, xv);
    dim3 cw(Dn * Dn / 1024, 4);                // (1024, 4)
    cvt_w<<<cw, 256, 0, stream>>>(W_Q, W_K, W_V, W_O, wq, wk, wv, wo);

    dim3 gq(Dn / 128, Mn / 128, 3);            // (8, 32, 3) = 768 blocks
    gemm_qkv<<<gq, 256, 0, stream>>>(xq, xk, xv, wq, wk, wv,
                                     b_Q, b_K, b_V, q_t, k_t, v_ln);

    dim3 tg(32, Ln / 64);                      // (32, 32)
    transpose_v<<<tg, 256, 0, stream>>>(v_ln, v_T);

    dim3 ag(32, Ln / 128);                     // (32, 16) = 512 blocks
    attn_mfma<<<ag, 256, 0, stream>>>(q_t, k_t, v_T, cat);

    dim3 go(Dn / 128, Mn / 64);                // (8, 64) = 512 blocks
    gemm_o<<<go, 256, 0, stream>>>(cat, wo, b_O, (float*)d_out);
    lorentz_row_full<<<Mn, 256, 0, stream>>>((float*)d_out);
}

// Round 6
// 157.161 us; speedup vs baseline: 16.1535x; 1.0231x over previous
//
#include <hip/hip_runtime.h>
#include <math.h>

namespace {
constexpr int Ln = 2048;
constexpr int Dn = 1024;
constexpr int Mn = 4096;   // B*L
constexpr float QSCALE = 0.25f * 1.44269504088896340736f; // 2/sqrt(64) * log2(e)
}

typedef unsigned short u16;
typedef unsigned int u32;
typedef __attribute__((ext_vector_type(4))) float f32x4;
typedef __attribute__((ext_vector_type(8))) __bf16 bf16x8;
typedef __attribute__((ext_vector_type(4))) unsigned short u16x4;
typedef __attribute__((ext_vector_type(8))) unsigned short u16x8;
typedef __attribute__((ext_vector_type(4))) unsigned int u32x4;

// ============================================================================
// LAYOUT CONVENTIONS (write-side must match read-side):
// * bf16 matrices staged into LDS by global_load_lds are stored in global
//   PRE-SWIZZLED: within each 64-element (128B) k-slice of a row l, the
//   16B block b is stored at position b ^ (l&7).  Readers of an LDS tile
//   apply the same XOR with the local row (tiles are 8-row aligned).
// * Q/K projections store head features in SLOT order s = 4*(d&15) + (d>>4).
//   Q and K share the permutation => dot products unchanged.  V stored same
//   way; transpose_v un-permutes.  cat (attn output) uses the same slot
//   order per head, compensated by permuting W_O's input columns.
// * v_T ([bh][d][2048]) position y within each 64-chunk holds physical key
//   nu(y) = (y>>5)*32 + ((y>>2)&1)*16 + ((y>>3)&3)*4 + (y&3).
//   This makes the PV A-fragment (lane c,g; elem e of half kk) equal
//   exp2(sf[2kk + (e>>2)][e&3]) of the SAME lane after the swapped QK^T
//   mfma(K,Q) -> pure-register softmax->P, zero LDS round-trip.
// ============================================================================

__device__ __forceinline__ u16 f2bf(float f) {
    union { float f; unsigned u; } cv; cv.f = f;
    unsigned u = cv.u + 0x7fffu + ((cv.u >> 16) & 1u);
    return (u16)(u >> 16);
}

__device__ __forceinline__ u32 pkbf(float a, float b) {
    union { __bf16 h[2]; u32 u; } cv;
    cv.h[0] = (__bf16)a; cv.h[1] = (__bf16)b;
    return cv.u;
}

// DPP cross-lane (16-lane row) sum — VALU pipe, no LDS
template <int CTRL>
__device__ __forceinline__ float dppf(float x) {
    return __int_as_float(__builtin_amdgcn_update_dpp(
        0, __float_as_int(x), CTRL, 0xf, 0xf, true));
}
__device__ __forceinline__ float red16_add(float x) {
    x += dppf<0xB1>(x);    // quad_perm(1,0,3,2)
    x += dppf<0x4E>(x);    // quad_perm(2,3,0,1)
    x += dppf<0x141>(x);   // row_half_mirror
    x += dppf<0x140>(x);   // row_mirror
    return x;
}

__device__ __forceinline__ void gload16(const void* g, void* l) {
    __builtin_amdgcn_global_load_lds(
        (const __attribute__((address_space(1))) unsigned int*)g,
        (__attribute__((address_space(3))) unsigned int*)l, 16, 0, 0);
}

// ---------------------------------------------------------------------------
// f32 -> bf16 convert of the 3 inputs, swizzled global layout (rows of 1024).
// ---------------------------------------------------------------------------
__global__ __launch_bounds__(256)
void cvt_in3(const float* __restrict__ i0, const float* __restrict__ i1,
             const float* __restrict__ i2,
             u16* __restrict__ o0, u16* __restrict__ o1, u16* __restrict__ o2)
{
    const int z = blockIdx.y;
    const float* in = z == 0 ? i0 : (z == 1 ? i1 : i2);
    u16* out       = z == 0 ? o0 : (z == 1 ? o1 : o2);
    int i = blockIdx.x * 256 + threadIdx.x;        // group of 4 elements
    f32x4 v = ((const f32x4*)in)[i];
    u16x4 o;
#pragma unroll
    for (int j = 0; j < 4; ++j) o[j] = f2bf(v[j]);
    int l = i >> 8;                // row
    int e = (i & 255) * 4;         // element within row
    int idx = l * 1024 + (e & ~63) + (((((e >> 3) & 7) ^ (l & 7))) << 3) + (e & 7);
    *(u16x4*)&out[idx] = o;
}

// ---------------------------------------------------------------------------
// Weights cvt: wq/wk/wv plain swizzle; wo (z==3) also permutes input columns
// to cat's per-head slot order.
// ---------------------------------------------------------------------------
__global__ __launch_bounds__(256)
void cvt_w(const float* __restrict__ w0, const float* __restrict__ w1,
           const float* __restrict__ w2, const float* __restrict__ w3,
           u16* __restrict__ q0, u16* __restrict__ q1,
           u16* __restrict__ q2, u16* __restrict__ q3)
{
    const int z = blockIdx.y;
    int i = blockIdx.x * 256 + threadIdx.x;
    if (z < 3) {
        const float* in = z == 0 ? w0 : (z == 1 ? w1 : w2);
        u16* out       = z == 0 ? q0 : (z == 1 ? q1 : q2);
        f32x4 v = ((const f32x4*)in)[i];
        u16x4 o;
#pragma unroll
        for (int j = 0; j < 4; ++j) o[j] = f2bf(v[j]);
        int l = i >> 8;
        int e = (i & 255) * 4;
        int idx = l * 1024 + (e & ~63) + (((((e >> 3) & 7) ^ (l & 7))) << 3) + (e & 7);
        *(u16x4*)&out[idx] = o;
    } else {
        int o  = i >> 8;             // output row of W_O (natural)
        int s0 = (i & 255) * 4;      // out column-slot base
        int h = s0 >> 6, sl = s0 & 63, a = sl >> 2;
        const float* src = w3 + (size_t)o * 1024 + h * 64;
        // slot s0+j holds input feature h*64 + j*16 + a
        u16x4 ov = { f2bf(src[a]), f2bf(src[16 + a]),
                     f2bf(src[32 + a]), f2bf(src[48 + a]) };
        int idx = o * 1024 + h * 64 + (((sl >> 3) ^ (o & 7)) << 3) + (sl & 7);
        *(u16x4*)&q3[idx] = ov;
    }
}

// ---------------------------------------------------------------------------
// Q/K/V projection GEMM + fused per-head Lorentz projection.
// 128x128 tile, BK=64, 256 thr (4 waves 2x2).  Output bf16 [b][h][l][64slots],
// slot-permuted + byte-swizzled, packed b64 stores.
// ---------------------------------------------------------------------------
__device__ __forceinline__
void gemm_proj_body(const u16* __restrict__ A, const u16* __restrict__ W,
                    const float* __restrict__ bias, u16* __restrict__ Ct,
                    float scale, float tsign, u16* As, u16* Bs)
{
    const int t = threadIdx.x;
    const int lane = t & 63, w = t >> 6;
    const int g = lane >> 4, c = lane & 15;
    const int wr = w >> 1, wc = w & 1;
    const int bm = blockIdx.y * 128, bn = blockIdx.x * 128;

    f32x4 acc[4][4];
    const f32x4 z4 = {0.f, 0.f, 0.f, 0.f};
#pragma unroll
    for (int i = 0; i < 4; ++i)
#pragma unroll
        for (int j = 0; j < 4; ++j) acc[i][j] = z4;

    for (int k0 = 0; k0 < Dn; k0 += 64) {
        __syncthreads();
#pragma unroll
        for (int p = 0; p < 4; ++p) {
            int ci = p * 256 + t;
            int r = ci >> 3, bq = ci & 7;
            gload16(A + (size_t)(bm + r) * Dn + k0 + bq * 8, &As[ci * 8]);
            gload16(W + (size_t)(bn + r) * Dn + k0 + bq * 8, &Bs[ci * 8]);
        }
        __syncthreads();
#pragma unroll
        for (int kk = 0; kk < 2; ++kk) {
            bf16x8 a[4], b[4];
#pragma unroll
            for (int mi = 0; mi < 4; ++mi)
                a[mi] = *(const bf16x8*)&As[(wr * 64 + mi * 16 + c) * 64 +
                                            (((kk * 4 + g) ^ (c & 7)) << 3)];
#pragma unroll
            for (int ni = 0; ni < 4; ++ni)
                b[ni] = *(const bf16x8*)&Bs[(wc * 64 + ni * 16 + c) * 64 +
                                            (((kk * 4 + g) ^ (c & 7)) << 3)];
            __builtin_amdgcn_s_setprio(1);
#pragma unroll
            for (int mi = 0; mi < 4; ++mi)
#pragma unroll
                for (int ni = 0; ni < 4; ++ni)
                    acc[mi][ni] = __builtin_amdgcn_mfma_f32_16x16x32_bf16(
                        a[mi], b[ni], acc[mi][ni], 0, 0, 0);
            __builtin_amdgcn_s_setprio(0);
        }
    }

    const int hcb = bn + wc * 64;
    const int h = hcb >> 6;
#pragma unroll
    for (int mi = 0; mi < 4; ++mi)
#pragma unroll
        for (int j = 0; j < 4; ++j) {
            int ll = bm + wr * 64 + mi * 16 + g * 4 + j;
            float zv[4];
#pragma unroll
            for (int ni = 0; ni < 4; ++ni)
                zv[ni] = acc[mi][ni][j] + bias[hcb + ni * 16 + c];
            float loc = zv[0]*zv[0] + zv[1]*zv[1] + zv[2]*zv[2] + zv[3]*zv[3];
            if (c == 0) loc -= zv[0] * zv[0];     // z0 is DISCARDED (once!)
            loc = red16_add(loc);                 // = sum of space^2
            float tval = sqrtf(1.f + loc);
            float v0 = (c == 0) ? tsign * tval : zv[0];
            int bb = ll >> 11, l2 = ll & 2047;
            u16* dst = Ct + (((size_t)bb * 16 + h) * Ln + l2) * 64;
            u16x4 pkv = { f2bf(v0 * scale), f2bf(zv[1] * scale),
                          f2bf(zv[2] * scale), f2bf(zv[3] * scale) };
            *(u16x4*)&dst[(4 * c) ^ ((ll & 7) << 3)] = pkv;
        }
}

__global__ __launch_bounds__(256)
void gemm_qkv(const u16* __restrict__ xq, const u16* __restrict__ xk,
              const u16* __restrict__ xv, const u16* __restrict__ wq,
              const u16* __restrict__ wk, const u16* __restrict__ wv,
              const float* __restrict__ bq, const float* __restrict__ bk,
              const float* __restrict__ bv,
              u16* __restrict__ oq, u16* __restrict__ ok, u16* __restrict__ ov)
{
    __shared__ u16 As[128 * 64];
    __shared__ u16 Bs[128 * 64];
    const int z = blockIdx.z;
    const u16* A = z == 0 ? xq : (z == 1 ? xk : xv);
    const u16* W = z == 0 ? wq : (z == 1 ? wk : wv);
    const float* bb = z == 0 ? bq : (z == 1 ? bk : bv);
    u16* O = z == 0 ? oq : (z == 1 ? ok : ov);
    gemm_proj_body(A, W, bb, O, z == 0 ? QSCALE : 1.f, z == 0 ? -1.f : 1.f, As, Bs);
}

// ---------------------------------------------------------------------------
// V transpose: [bh][l][64 slots,swz] -> v_T [bh][d][2048] where position y
// within each 64-chunk holds key nu(y) (see header), byte-swizzled per (d&7).
// ---------------------------------------------------------------------------
__global__ __launch_bounds__(256)
void transpose_v(const u16* __restrict__ vin, u16* __restrict__ vout)
{
    __shared__ u16 raw[64 * 64];     // straight copy of the swizzled tile
    const int t = threadIdx.x;
    const int bh = blockIdx.x, lc = blockIdx.y;
    const u16* src = vin + ((size_t)bh * Ln + lc * 64) * 64;
#pragma unroll
    for (int p = 0; p < 2; ++p) {
        int ci = p * 256 + t;
        *(u16x8*)&raw[ci * 8] = *(const u16x8*)(src + ci * 8);
    }
    __syncthreads();
    const int d = t >> 2, cp0 = (t & 3) * 16;
    const int s = ((d & 15) << 2) | (d >> 4);   // slot of true feature d
    u16 buf[16];
#pragma unroll
    for (int i = 0; i < 16; ++i) {
        int cp = cp0 + i;
        // physical key for v_T position cp:
        int n = ((cp >> 5) << 5) | (((cp >> 2) & 1) << 4) | (((cp >> 3) & 3) << 2) | (cp & 3);
        buf[i] = raw[n * 64 + ((((s >> 3) ^ (n & 7)) << 3) | (s & 7))];
    }
    u16* dst = vout + ((size_t)bh * 64 + d) * Ln + lc * 64;
    int b0 = cp0 >> 3;
    *(u16x8*)&dst[((b0 ^ (d & 7)) << 3)]       = *(const u16x8*)&buf[0];
    *(u16x8*)&dst[(((b0 + 1) ^ (d & 7)) << 3)] = *(const u16x8*)&buf[8];
}

// ---------------------------------------------------------------------------
// MFMA flash attention per (b,h).  4 waves x 32 q-rows = 128 q/block.
// K/V staged direct global->LDS (pre-swizzled source), double-buffered,
// one barrier per 64-KV chunk.  SWAPPED QK^T (mfma(K,Q)) => S^T in regs;
// fixed-max softmax (scores<=0) + nu-permuted V => P fragments assembled
// ENTIRELY in registers (exp2 + cvt_pk), zero P LDS traffic.  No softmax
// denominator (mu/||mu|| is scale-invariant).  Epilogue: Lorentz normalize,
// packed b64 slot-stores into cat (swizzled for O-GEMM staging).
// ---------------------------------------------------------------------------
__global__ __launch_bounds__(256)
void attn_mfma(const u16* __restrict__ qt, const u16* __restrict__ kt,
               const u16* __restrict__ vT, u16* __restrict__ cat)
{
    __shared__ u16 k_s[2][64 * 64];
    __shared__ u16 v_s[2][64 * 64];

    const int t = threadIdx.x;
    const int lane = t & 63, w = t >> 6;
    const int g = lane >> 4, c = lane & 15;
    const int bh = blockIdx.x;
    const int q0 = blockIdx.y * 128;
    const u16* Q = qt + (size_t)bh * Ln * 64;
    const u16* K = kt + (size_t)bh * Ln * 64;
    const u16* V = vT + (size_t)bh * 64 * (size_t)Ln;

    // Q fragments (2 row-frags x 2 k-halves) in registers for the whole sweep
    bf16x8 qa[2][2];
#pragma unroll
    for (int mi = 0; mi < 2; ++mi)
#pragma unroll
        for (int kk = 0; kk < 2; ++kk) {
            int row = q0 + w * 32 + mi * 16 + c;
            qa[mi][kk] = *(const bf16x8*)(Q + (size_t)row * 64 +
                                          (((kk * 4 + g) ^ (c & 7)) << 3));
        }

    f32x4 o[2][4];
    const f32x4 z4 = {0.f, 0.f, 0.f, 0.f};
#pragma unroll
    for (int mi = 0; mi < 2; ++mi)
#pragma unroll
        for (int di = 0; di < 4; ++di) o[mi][di] = z4;

    const int cr = t >> 3, cb = t & 7;    // staging: row piece / 16B block

    // prologue: stage chunk 0 into buffer 0
#pragma unroll
    for (int p = 0; p < 2; ++p) {
        int r = p * 32 + cr;
        gload16(K + (size_t)r * 64 + cb * 8, &k_s[0][(p * 256 + t) * 8]);
        gload16(V + (size_t)r * Ln + cb * 8, &v_s[0][(p * 256 + t) * 8]);
    }

    constexpr int NC = Ln / 64;
    for (int ch = 0; ch < NC; ++ch) {
        const int cur = ch & 1;
        __syncthreads();   // staged chunk ch visible (drains gloads), prior reads done
        if (ch + 1 < NC) { // issue next-chunk staging; lands by next barrier
#pragma unroll
            for (int p = 0; p < 2; ++p) {
                int r = p * 32 + cr;
                gload16(K + (size_t)((ch + 1) * 64 + r) * 64 + cb * 8,
                        &k_s[cur ^ 1][(p * 256 + t) * 8]);
                gload16(V + (size_t)r * Ln + (ch + 1) * 64 + cb * 8,
                        &v_s[cur ^ 1][(p * 256 + t) * 8]);
            }
        }
        const u16* ks = k_s[cur];
        const u16* vs = v_s[cur];

        // ---- QK^T swapped: sf[mi][ni][j] = S[k=16ni+4g+j][q=16mi+c] ----
        f32x4 sf[2][4];
#pragma unroll
        for (int mi = 0; mi < 2; ++mi)
#pragma unroll
            for (int ni = 0; ni < 4; ++ni) sf[mi][ni] = z4;
        __builtin_amdgcn_s_setprio(1);
#pragma unroll
        for (int kk = 0; kk < 2; ++kk) {
            bf16x8 kb[4];
#pragma unroll
            for (int ni = 0; ni < 4; ++ni) {
                int n = ni * 16 + c;
                kb[ni] = *(const bf16x8*)&ks[n * 64 +
                    (((kk * 64 + g * 16) ^ ((c & 7) << 4)) >> 1)];
            }
#pragma unroll
            for (int mi = 0; mi < 2; ++mi)
#pragma unroll
                for (int ni = 0; ni < 4; ++ni)
                    sf[mi][ni] = __builtin_amdgcn_mfma_f32_16x16x32_bf16(
                        kb[ni], qa[mi][kk], sf[mi][ni], 0, 0, 0);
        }
        __builtin_amdgcn_s_setprio(0);

        // ---- softmax numerator (fixed max 0) + P frags in registers ----
        bf16x8 paf[2][2];
#pragma unroll
        for (int mi = 0; mi < 2; ++mi) {
            float ex[4][4];
#pragma unroll
            for (int ni = 0; ni < 4; ++ni)
#pragma unroll
                for (int j = 0; j < 4; ++j)
                    ex[ni][j] = exp2f(sf[mi][ni][j]);
            u32x4 p0 = { pkbf(ex[0][0], ex[0][1]), pkbf(ex[0][2], ex[0][3]),
                         pkbf(ex[1][0], ex[1][1]), pkbf(ex[1][2], ex[1][3]) };
            u32x4 p1 = { pkbf(ex[2][0], ex[2][1]), pkbf(ex[2][2], ex[2][3]),
                         pkbf(ex[3][0], ex[3][1]), pkbf(ex[3][2], ex[3][3]) };
            paf[mi][0] = __builtin_bit_cast(bf16x8, p0);
            paf[mi][1] = __builtin_bit_cast(bf16x8, p1);
        }

        // ---- PV (16 MFMA): O[q][d] += P[q][k] V[k][d] ----
        __builtin_amdgcn_s_setprio(1);
#pragma unroll
        for (int kk = 0; kk < 2; ++kk)
#pragma unroll
            for (int di = 0; di < 4; ++di) {
                int d = di * 16 + c;
                bf16x8 vb = *(const bf16x8*)&vs[d * 64 +
                    (((kk * 64 + g * 16) ^ ((c & 7) << 4)) >> 1)];
#pragma unroll
                for (int mi = 0; mi < 2; ++mi)
                    o[mi][di] = __builtin_amdgcn_mfma_f32_16x16x32_bf16(
                        paf[mi][kk], vb, o[mi][di], 0, 0, 0);
            }
        __builtin_amdgcn_s_setprio(0);
    }

    // ---- epilogue: Lorentz normalize o (scale-invariant), write cat ----
    const int b = bh >> 4, h = bh & 15;
#pragma unroll
    for (int mi = 0; mi < 2; ++mi)
#pragma unroll
        for (int j = 0; j < 4; ++j) {
            float mu[4];
#pragma unroll
            for (int di = 0; di < 4; ++di) mu[di] = o[mi][di][j];
            float loc = mu[0]*mu[0] + mu[1]*mu[1] + mu[2]*mu[2] + mu[3]*mu[3];
            if (c == 0) loc -= 2.f * mu[0] * mu[0];   // Lorentz inner <o,o>
            loc = red16_add(loc);
            float rn = rsqrtf(fmaxf(fabsf(loc), 1e-6f));
            int row = q0 + w * 32 + mi * 16 + g * 4 + j;
            u16* dst = cat + ((size_t)b * Ln + row) * Dn + h * 64;
            u16x4 pkv = { f2bf(mu[0] * rn), f2bf(mu[1] * rn),
                          f2bf(mu[2] * rn), f2bf(mu[3] * rn) };
            *(u16x4*)&dst[(4 * c) ^ ((row & 7) << 3)] = pkv;
        }
}

// ---------------------------------------------------------------------------
// Output GEMM: out[4096][1024] = cat @ wo^T + b_O (f32 out).
// 64x128 tile, BK=64, 512 blocks (2/CU).
// ---------------------------------------------------------------------------
__global__ __launch_bounds__(256)
void gemm_o(const u16* __restrict__ A, const u16* __restrict__ B,
            const float* __restrict__ bias, float* __restrict__ C)
{
    __shared__ u16 As[64 * 64];
    __shared__ u16 Bs[128 * 64];
    const int t = threadIdx.x;
    const int lane = t & 63, w = t >> 6;
    const int g = lane >> 4, c = lane & 15;
    const int wr = w >> 1, wc = w & 1;
    const int bm = blockIdx.y * 64, bn = blockIdx.x * 128;

    f32x4 acc[2][4];
    const f32x4 z4 = {0.f, 0.f, 0.f, 0.f};
#pragma unroll
    for (int i = 0; i < 2; ++i)
#pragma unroll
        for (int j = 0; j < 4; ++j) acc[i][j] = z4;

    for (int k0 = 0; k0 < Dn; k0 += 64) {
        __syncthreads();
#pragma unroll
        for (int p = 0; p < 2; ++p) {
            int ci = p * 256 + t;
            gload16(A + (size_t)(bm + (ci >> 3)) * Dn + k0 + (ci & 7) * 8,
                    &As[ci * 8]);
        }
#pragma unroll
        for (int p = 0; p < 4; ++p) {
            int ci = p * 256 + t;
            gload16(B + (size_t)(bn + (ci >> 3)) * Dn + k0 + (ci & 7) * 8,
                    &Bs[ci * 8]);
        }
        __syncthreads();
#pragma unroll
        for (int kk = 0; kk < 2; ++kk) {
            bf16x8 a[2], b[4];
#pragma unroll
            for (int mi = 0; mi < 2; ++mi)
                a[mi] = *(const bf16x8*)&As[(wr * 32 + mi * 16 + c) * 64 +
                                            (((kk * 4 + g) ^ (c & 7)) << 3)];
#pragma unroll
            for (int ni = 0; ni < 4; ++ni)
                b[ni] = *(const bf16x8*)&Bs[(wc * 64 + ni * 16 + c) * 64 +
                                            (((kk * 4 + g) ^ (c & 7)) << 3)];
            __builtin_amdgcn_s_setprio(1);
#pragma unroll
            for (int mi = 0; mi < 2; ++mi)
#pragma unroll
                for (int ni = 0; ni < 4; ++ni)
                    acc[mi][ni] = __builtin_amdgcn_mfma_f32_16x16x32_bf16(
                        a[mi], b[ni], acc[mi][ni], 0, 0, 0);
            __builtin_amdgcn_s_setprio(0);
        }
    }

#pragma unroll
    for (int mi = 0; mi < 2; ++mi)
#pragma unroll
        for (int j = 0; j < 4; ++j) {
            size_t row = bm + wr * 32 + mi * 16 + g * 4 + j;
#pragma unroll
            for (int ni = 0; ni < 4; ++ni) {
                int col = bn + wc * 64 + ni * 16 + c;
                C[row * Dn + col] = acc[mi][ni][j] + bias[col];
            }
        }
}

// ---------------------------------------------------------------------------
// Full-row (D=1024) Lorentz projection on f32 output rows.
// ---------------------------------------------------------------------------
__global__ __launch_bounds__(256)
void lorentz_row_full(float* __restrict__ z)
{
    __shared__ float red[4];
    const int t = threadIdx.x;
    const size_t base = (size_t)blockIdx.x * Dn;
    float4 v = *(const float4*)&z[base + t * 4];
    if (t == 0) v.x = 0.f;
    float ssq = v.x * v.x + v.y * v.y + v.z * v.z + v.w * v.w;
#pragma unroll
    for (int off = 32; off; off >>= 1) ssq += __shfl_xor(ssq, off);
    if ((t & 63) == 0) red[t >> 6] = ssq;
    __syncthreads();
    if (t == 0) z[base] = sqrtf(1.0f + red[0] + red[1] + red[2] + red[3]);
}

// ---------------------------------------------------------------------------
extern "C" void kernel_launch(void* const* d_in, const int* in_sizes, int n_in,
                              void* d_out, int out_size, void* d_ws, size_t ws_size,
                              hipStream_t stream)
{
    const float* query = (const float*)d_in[0];
    const float* key_  = (const float*)d_in[1];
    const float* value = (const float*)d_in[2];
    const float* W_Q   = (const float*)d_in[3];
    const float* b_Q   = (const float*)d_in[4];
    const float* W_K   = (const float*)d_in[5];
    const float* b_K   = (const float*)d_in[6];
    const float* W_V   = (const float*)d_in[7];
    const float* b_V   = (const float*)d_in[8];
    const float* W_O   = (const float*)d_in[9];
    const float* b_O   = (const float*)d_in[10];

    u16* xq   = (u16*)d_ws;                    // bf16 inputs (swz) [4096][1024]
    u16* xk   = xq  + (size_t)Mn * Dn;
    u16* xv   = xk  + (size_t)Mn * Dn;
    u16* wq   = xv  + (size_t)Mn * Dn;         // bf16 weights (swz) [1024][1024]
    u16* wk   = wq  + (size_t)Dn * Dn;
    u16* wv   = wk  + (size_t)Dn * Dn;
    u16* wo   = wv  + (size_t)Dn * Dn;         // + column slot-perm
    u16* q_t  = wo  + (size_t)Dn * Dn;         // bf16 [b][h][l][64slots]
    u16* k_t  = q_t + (size_t)Mn * Dn;
    u16* v_ln = k_t + (size_t)Mn * Dn;         // V projection, [b][h][l][64slots]
    u16* v_T  = xv;                            // alias: xv dead after gemm_qkv
    u16* cat  = xk;                            // alias: xk dead after gemm_qkv

    dim3 ci(Mn * Dn / 1024, 3);                // (4096, 3)
    cvt_in3<<<ci, 256, 0, stream>>>(query, key_, value, xq, xk, xv);
    dim3 cw(Dn * Dn / 1024, 4);                // (1024, 4)
    cvt_w<<<cw, 256, 0, stream>>>(W_Q, W_K, W_V, W_O, wq, wk, wv, wo);

    dim3 gq(Dn / 128, Mn / 128, 3);            // (8, 32, 3) = 768 blocks
    gemm_qkv<<<gq, 256, 0, stream>>>(xq, xk, xv, wq, wk, wv,
                                     b_Q, b_K, b_V, q_t, k_t, v_ln);

    dim3 tg(32, Ln / 64);                      // (32, 32)
    transpose_v<<<tg, 256, 0, stream>>>(v_ln, v_T);

    dim3 ag(32, Ln / 128);                     // (32, 16) = 512 blocks
    attn_mfma<<<ag, 256, 0, stream>>>(q_t, k_t, v_T, cat);

    dim3 go(Dn / 128, Mn / 64);                // (8, 64) = 512 blocks
    gemm_o<<<go, 256, 0, stream>>>(cat, wo, b_O, (float*)d_out);
    lorentz_row_full<<<Mn, 256, 0, stream>>>((float*)d_out);
}